// Round 10
// baseline (314.923 us; speedup 1.0000x reference)
//
#include <hip/hip_runtime.h>
#include <cstdint>
#include <cstddef>

typedef unsigned short u16;
typedef __attribute__((ext_vector_type(4))) float floatx4;
typedef __attribute__((ext_vector_type(8))) __bf16 bf16x8;

// ---------- bf16 helpers ----------
__device__ __forceinline__ float u2f(u16 u) {
    union { unsigned int i; float f; } x;
    x.i = ((unsigned int)u) << 16;
    return x.f;
}
__device__ __forceinline__ u16 f2u(float f) {
    union { float f; unsigned int i; } x;
    x.f = f;
    unsigned int r = x.i + 0x7fffu + ((x.i >> 16) & 1u);   // RNE
    return (u16)(r >> 16);
}

// ---------- XCD-aware swizzle: bid -> (x,y); XCD k owns y-strip [4k,4k+4), x-major ----------
__device__ __forceinline__ void swz(int bid, int& x, int& y) {
    int xcd = bid & 7;
    int lid = bid >> 3;
    x = lid >> 2;
    y = xcd * 4 + (lid & 3);
}

// ---------- prep: 3 weight transposes + B_mat cast-copy/pad + layernorm(+out=x) ----------
__device__ __forceinline__ void tr_tile(const float* __restrict__ in, u16* __restrict__ out,
                                        int K, int N, int bx, int by, float* tile /*32x33*/) {
    int n0 = bx * 32, k0 = by * 32;
    int t = threadIdx.x;
    int r = t >> 3, c4 = (t & 7) * 4;          // input row k0+r, cols n0+c4..+3
    float4 v = *(const float4*)(in + (size_t)(k0 + r) * N + n0 + c4);
    tile[r * 33 + c4 + 0] = v.x;
    tile[r * 33 + c4 + 1] = v.y;
    tile[r * 33 + c4 + 2] = v.z;
    tile[r * 33 + c4 + 3] = v.w;
    __syncthreads();
    int n = t >> 3, kg = (t & 7) * 4;          // output row n0+n, k cols k0+kg..+3
    ushort4 o;
    o.x = f2u(tile[(kg + 0) * 33 + n]);
    o.y = f2u(tile[(kg + 1) * 33 + n]);
    o.z = f2u(tile[(kg + 2) * 33 + n]);
    o.w = f2u(tile[(kg + 3) * 33 + n]);
    *(ushort4*)(out + (size_t)(n0 + n) * K + k0 + kg) = o;
}

// blocks: [0,4096) W_in tr; [4096,8192) Wd tr (rows 0..2047 of Wt_ext);
//         [8192,10240) W_out tr; [10240,14336) layernorm; [14336,14848) B_mat copy+pad (64 rows)
__global__ __launch_bounds__(256)
void prep_kernel(const float* __restrict__ W_in, u16* __restrict__ Wt_in,
                 const float* __restrict__ Wd, u16* __restrict__ Wt_ext,
                 const float* __restrict__ W_out, u16* __restrict__ Wt_out,
                 const float* __restrict__ B_mat,
                 const float* __restrict__ x, const float* __restrict__ gamma,
                 const float* __restrict__ beta, u16* __restrict__ h,
                 float* __restrict__ out) {
    __shared__ float tile[32 * 33];
    int blk = blockIdx.x, t = threadIdx.x;
    if (blk < 4096) {
        tr_tile(W_in, Wt_in, 1024, 4096, blk & 127, blk >> 7, tile);
    } else if (blk < 8192) {
        int b2 = blk - 4096;
        tr_tile(Wd, Wt_ext, 2048, 2048, b2 & 63, b2 >> 6, tile);
    } else if (blk < 10240) {
        int b3 = blk - 8192;
        tr_tile(W_out, Wt_out, 2048, 1024, b3 & 31, b3 >> 5, tile);
    } else if (blk < 14336) {
        int r = blk - 10240;
        const float4* xr = (const float4*)(x + (size_t)r * 1024);
        float4 xv = xr[t];
        ((float4*)(out + (size_t)r * 1024))[t] = xv;   // residual base (fin path adds)
        float s = xv.x + xv.y + xv.z + xv.w;
        float ss = xv.x * xv.x + xv.y * xv.y + xv.z * xv.z + xv.w * xv.w;
#pragma unroll
        for (int off = 32; off > 0; off >>= 1) {
            s += __shfl_down(s, off, 64);
            ss += __shfl_down(ss, off, 64);
        }
        __shared__ float rs[4], rss[4], mu_s, ri_s;
        int wave = t >> 6, lane = t & 63;
        if (lane == 0) { rs[wave] = s; rss[wave] = ss; }
        __syncthreads();
        if (t == 0) {
            float S = rs[0] + rs[1] + rs[2] + rs[3];
            float SS = rss[0] + rss[1] + rss[2] + rss[3];
            float mu = S * (1.f / 1024.f);
            float var = SS * (1.f / 1024.f) - mu * mu;
            mu_s = mu;
            ri_s = rsqrtf(fmaxf(var, 0.f) + 1e-5f);
        }
        __syncthreads();
        float mu = mu_s, ri = ri_s;
        float4 gv = ((const float4*)gamma)[t];
        float4 bv = ((const float4*)beta)[t];
        ushort4 o;
        o.x = f2u((xv.x - mu) * ri * gv.x + bv.x);
        o.y = f2u((xv.y - mu) * ri * gv.y + bv.y);
        o.z = f2u((xv.z - mu) * ri * gv.z + bv.z);
        o.w = f2u((xv.w - mu) * ri * gv.w + bv.w);
        ((ushort4*)(h + (size_t)r * 1024))[t] = o;
    } else {
        // Wt_ext rows 2048..2111: first 16 = B_mat (bf16 cast), rest zero pad
        int idx = (blk - 14336) * 256 + t;         // 0..131071
        int row = 2048 + (idx >> 11), col = idx & 2047;
        u16 v = (row < 2064) ? f2u(B_mat[(size_t)(row - 2048) * 2048 + col]) : (u16)0;
        Wt_ext[(size_t)row * 2048 + col] = v;
    }
}

__device__ __forceinline__ void gl_lds16(const u16* g, u16* l) {
    __builtin_amdgcn_global_load_lds(
        (const __attribute__((address_space(1))) void*)g,
        (__attribute__((address_space(3))) void*)l, 16, 0, 0);
}

// ================== 256x256 8-phase GEMM body (T2 col16-swizzled LDS) ==============
// 512 threads = 8 waves (wr=wid>>2 in {0,1}, wc=wid&3 in {0..3}); per-wave out 128x64.
// LDS 128 KB: As/Bs[2 bufs][2 kk-pages][256 rows][32 cols] bf16.
// T2 swizzle (rule #21: gl_lds16 dest linear, SOURCE pre-swizzled, READ swizzled):
//   LDS(row, c16) holds global(row, c16 ^ s(row)), s(row)=(row>>2)&3.
//   write: lane l dest row w*32+(l>>2) -> stage global col16 (l&3)^((l>>4)&3).
//   read: row=base+l16 (base multiple of 16) -> col16 q^((l16>>2)&3).
//   Bank spread: 16 lanes -> 8 banks x 2-way (free) vs 2 banks x 8-way (2.94x) before.
template <int CB, int NB>
__device__ __forceinline__
void ktile256(u16 (&As)[2][16384], u16 (&Bs)[2][16384],
              const u16* __restrict__ gA, const u16* __restrict__ gB,
              int kt, bool doStage, int K,
              int w, int wr, int wc, int l16, int qsw,
              floatx4 (&acc)[8][4]) {
    asm volatile("s_waitcnt vmcnt(0)" ::: "memory");
    __builtin_amdgcn_s_barrier();
    asm volatile("" ::: "memory");
    bf16x8 af[4][2], bfr[4][2];
    const int aBase = wr * 128, bBase = wc * 64;
    // ---- phase 0: read af(mi 0-3) + bfr(ni 0-1); stage A(kt+1) ----
#pragma unroll
    for (int i = 0; i < 4; ++i)
#pragma unroll
        for (int h = 0; h < 2; ++h)
            af[i][h] = *(const bf16x8*)&As[CB][h * 8192 + (aBase + i * 16 + l16) * 32 + qsw * 8];
#pragma unroll
    for (int j = 0; j < 2; ++j)
#pragma unroll
        for (int h = 0; h < 2; ++h)
            bfr[j][h] = *(const bf16x8*)&Bs[CB][h * 8192 + (bBase + j * 16 + l16) * 32 + qsw * 8];
    if (doStage) {
        const u16* p = gA + (size_t)(kt + 1) * 64;
#pragma unroll
        for (int h = 0; h < 2; ++h) {
            gl_lds16(p + h * 32,                  &As[NB][h * 8192 + w * 1024]);
            gl_lds16(p + (size_t)16 * K + h * 32, &As[NB][h * 8192 + w * 1024 + 512]);
        }
    }
    __builtin_amdgcn_s_barrier();
    __builtin_amdgcn_s_setprio(1);
#pragma unroll
    for (int i = 0; i < 4; ++i)
#pragma unroll
        for (int j = 0; j < 2; ++j)
#pragma unroll
            for (int h = 0; h < 2; ++h)
                acc[i][j] = __builtin_amdgcn_mfma_f32_16x16x32_bf16(af[i][h], bfr[j][h], acc[i][j], 0, 0, 0);
    __builtin_amdgcn_s_setprio(0);
    __builtin_amdgcn_s_barrier();
    // ---- phase 1: read bfr(ni 2-3); stage B(kt+1) ----
#pragma unroll
    for (int j = 2; j < 4; ++j)
#pragma unroll
        for (int h = 0; h < 2; ++h)
            bfr[j][h] = *(const bf16x8*)&Bs[CB][h * 8192 + (bBase + j * 16 + l16) * 32 + qsw * 8];
    if (doStage) {
        const u16* p = gB + (size_t)(kt + 1) * 64;
#pragma unroll
        for (int h = 0; h < 2; ++h) {
            gl_lds16(p + h * 32,                  &Bs[NB][h * 8192 + w * 1024]);
            gl_lds16(p + (size_t)16 * K + h * 32, &Bs[NB][h * 8192 + w * 1024 + 512]);
        }
    }
    __builtin_amdgcn_s_barrier();
    __builtin_amdgcn_s_setprio(1);
#pragma unroll
    for (int i = 0; i < 4; ++i)
#pragma unroll
        for (int j = 2; j < 4; ++j)
#pragma unroll
            for (int h = 0; h < 2; ++h)
                acc[i][j] = __builtin_amdgcn_mfma_f32_16x16x32_bf16(af[i][h], bfr[j][h], acc[i][j], 0, 0, 0);
    __builtin_amdgcn_s_setprio(0);
    __builtin_amdgcn_s_barrier();
    // ---- phase 2: read af(mi 4-7); mfma mi4-7 x ni0-1 ----
#pragma unroll
    for (int i = 0; i < 4; ++i)
#pragma unroll
        for (int h = 0; h < 2; ++h)
            af[i][h] = *(const bf16x8*)&As[CB][h * 8192 + (aBase + (4 + i) * 16 + l16) * 32 + qsw * 8];
    __builtin_amdgcn_s_barrier();
    __builtin_amdgcn_s_setprio(1);
#pragma unroll
    for (int i = 0; i < 4; ++i)
#pragma unroll
        for (int j = 0; j < 2; ++j)
#pragma unroll
            for (int h = 0; h < 2; ++h)
                acc[4 + i][j] = __builtin_amdgcn_mfma_f32_16x16x32_bf16(af[i][h], bfr[j][h], acc[4 + i][j], 0, 0, 0);
    __builtin_amdgcn_s_setprio(0);
    __builtin_amdgcn_s_barrier();
    // ---- phase 3: mfma mi4-7 x ni2-3 (no reads) ----
    __builtin_amdgcn_s_setprio(1);
#pragma unroll
    for (int i = 0; i < 4; ++i)
#pragma unroll
        for (int j = 2; j < 4; ++j)
#pragma unroll
            for (int h = 0; h < 2; ++h)
                acc[4 + i][j] = __builtin_amdgcn_mfma_f32_16x16x32_bf16(af[i][h], bfr[j][h], acc[4 + i][j], 0, 0, 0);
    __builtin_amdgcn_s_setprio(0);
    __builtin_amdgcn_s_barrier();
}

// shared 256x256 body; koff/Ksub for split-K; out = bf16 plane of stride N
__device__ __forceinline__
void gemm256_body(const u16* __restrict__ A, const u16* __restrict__ Bt,
                  u16* __restrict__ out, int M, int N, int K,
                  int koff, int Ksub, int bx, int by) {
    __shared__ u16 As[2][16384];   // 64 KB
    __shared__ u16 Bs[2][16384];   // 64 KB
    const int tid = threadIdx.x;
    const int w = tid >> 6, lane = tid & 63;
    const int wr = w >> 2, wc = w & 3;
    const int row0 = by * 256, col0 = bx * 256;
    const int l16 = lane & 15, q = lane >> 4;
    const int sRow = lane >> 2;
    const int sKsw = ((lane & 3) ^ ((lane >> 4) & 3)) * 8;   // T2 source swizzle
    const int qsw = q ^ ((l16 >> 2) & 3);                    // T2 read swizzle

    floatx4 acc[8][4];
#pragma unroll
    for (int i = 0; i < 8; ++i)
#pragma unroll
        for (int j = 0; j < 4; ++j) acc[i][j] = (floatx4){0.f, 0.f, 0.f, 0.f};

    const u16* gA = A + (size_t)(row0 + w * 32 + sRow) * K + koff + sKsw;
    const u16* gB = Bt + (size_t)(col0 + w * 32 + sRow) * K + koff + sKsw;

    // prologue: stage K-tile 0 into buf0 (8 loads/thread)
#pragma unroll
    for (int h = 0; h < 2; ++h) {
        gl_lds16(gA + h * 32,                  &As[0][h * 8192 + w * 1024]);
        gl_lds16(gA + (size_t)16 * K + h * 32, &As[0][h * 8192 + w * 1024 + 512]);
        gl_lds16(gB + h * 32,                  &Bs[0][h * 8192 + w * 1024]);
        gl_lds16(gB + (size_t)16 * K + h * 32, &Bs[0][h * 8192 + w * 1024 + 512]);
    }

    const int nkt = Ksub >> 6;   // must be even
    for (int t2 = 0; t2 < nkt; t2 += 2) {
        ktile256<0, 1>(As, Bs, gA, gB, t2, true, K, w, wr, wc, l16, qsw, acc);
        ktile256<1, 0>(As, Bs, gA, gB, t2 + 1, (t2 + 2) < nkt, K, w, wr, wc, l16, qsw, acc);
    }

    const int mB = row0 + wr * 128;
    const int nB = col0 + wc * 64 + l16;
#pragma unroll
    for (int mi = 0; mi < 8; ++mi)
#pragma unroll
        for (int ni = 0; ni < 4; ++ni)
#pragma unroll
            for (int rr = 0; rr < 4; ++rr)
                out[(size_t)(mB + mi * 16 + q * 4 + rr) * N + nB + ni * 16] =
                    f2u(acc[mi][ni][rr]);
}

// xg = h_ln @ Wt_in : M=N=4096, K=1024; grid 256 = 16x16 tiles, 1 block/CU.
__global__ __launch_bounds__(512, 2)
void gemm_xg256(const u16* __restrict__ A, const u16* __restrict__ Bt,
                u16* __restrict__ out, int M, int N, int K) {
    const int bid = blockIdx.x;
    const int xcd = bid & 7, lid = bid >> 3;       // per-XCD 2-row y-strips
    const int by = xcd * 2 + (lid & 1), bx = lid >> 1;
    gemm256_body(A, Bt, out, M, N, K, 0, K, bx, by);
}

// fin split-K=4 into bf16 planes via 256x256 8-phase body: grid (64,4) = 256 blocks (1/CU)
__global__ __launch_bounds__(512, 2)
void gemm_fin256(const u16* __restrict__ A, const u16* __restrict__ Bt,
                 u16* __restrict__ planes, int M, int N, int K, int Ksub) {
    u16* plane = planes + (size_t)blockIdx.y * M * N;
    const int bid = blockIdx.x;                    // 0..63
    const int bx = bid >> 4, by = bid & 15;        // 4 N-tiles x 16 M-tiles
    gemm256_body(A, Bt, plane, M, N, K, blockIdx.y * Ksub, Ksub, bx, by);
}

// ---------- 128x128 tile GEMM, BK=64, 4 waves x (4x4 frags), 32 KB LDS ----------
// EPI 0: bf16 store;  EPI 4: atomicAdd f32 (fallback fin)
template <int EPI>
__device__ __forceinline__
void gemm128_body(const u16* __restrict__ A, const u16* __restrict__ Bt,
                  void* __restrict__ out, int M, int N, int K, int Ksub) {
    __shared__ u16 As[128 * 64];
    __shared__ u16 Bs[128 * 64];
    int bx, by;
    swz(blockIdx.x, bx, by);
    const int tid = threadIdx.x;
    const int wave = tid >> 6, lane = tid & 63;
    const int row0 = by * 128, col0 = bx * 128;
    const int koff = blockIdx.y * Ksub;
    const int l16 = lane & 15, q = lane >> 4;
    const int sRow = lane >> 2, sK = (lane & 3) * 8;

    floatx4 acc[4][4];
#pragma unroll
    for (int i = 0; i < 4; ++i)
#pragma unroll
        for (int j = 0; j < 4; ++j) acc[i][j] = (floatx4){0.f, 0.f, 0.f, 0.f};

    const u16* gA = A + (size_t)(row0 + wave * 32 + sRow) * K + koff + sK;
    const u16* gB = Bt + (size_t)(col0 + wave * 32 + sRow) * K + koff + sK;
    u16* lA = As + wave * 1024;
    u16* lB = Bs + wave * 1024;
    const int rowb = (wave >> 1) * 64, colb = (wave & 1) * 64;

    for (int k0 = 0; k0 < Ksub; k0 += 64) {
#pragma unroll
        for (int h = 0; h < 2; ++h) {
            gl_lds16(gA + h * 32, lA + h * 4096);
            gl_lds16(gA + (size_t)16 * K + h * 32, lA + h * 4096 + 512);
            gl_lds16(gB + h * 32, lB + h * 4096);
            gl_lds16(gB + (size_t)16 * K + h * 32, lB + h * 4096 + 512);
        }
        gA += 64; gB += 64;
        __syncthreads();
#pragma unroll
        for (int h = 0; h < 2; ++h) {
            bf16x8 af[4], bfr[4];
#pragma unroll
            for (int mi = 0; mi < 4; ++mi)
                af[mi] = *(const bf16x8*)(As + h * 4096 + (rowb + mi * 16 + l16) * 32 + q * 8);
#pragma unroll
            for (int ni = 0; ni < 4; ++ni)
                bfr[ni] = *(const bf16x8*)(Bs + h * 4096 + (colb + ni * 16 + l16) * 32 + q * 8);
#pragma unroll
            for (int mi = 0; mi < 4; ++mi)
#pragma unroll
                for (int ni = 0; ni < 4; ++ni)
                    acc[mi][ni] = __builtin_amdgcn_mfma_f32_16x16x32_bf16(
                        af[mi], bfr[ni], acc[mi][ni], 0, 0, 0);
        }
        __syncthreads();
    }

    const int mB = row0 + rowb;
    const int nB = col0 + colb + l16;
    if constexpr (EPI == 0) {
        u16* o = (u16*)out;
#pragma unroll
        for (int mi = 0; mi < 4; ++mi)
#pragma unroll
            for (int ni = 0; ni < 4; ++ni)
#pragma unroll
                for (int rr = 0; rr < 4; ++rr)
                    o[(size_t)(mB + mi * 16 + q * 4 + rr) * N + nB + ni * 16] =
                        f2u(acc[mi][ni][rr]);
    } else {
        float* C = (float*)out;
#pragma unroll
        for (int mi = 0; mi < 4; ++mi)
#pragma unroll
            for (int ni = 0; ni < 4; ++ni)
#pragma unroll
                for (int rr = 0; rr < 4; ++rr)
                    atomicAdd(&C[(size_t)(mB + mi * 16 + q * 4 + rr) * N + nB + ni * 16],
                              acc[mi][ni][rr]);
    }
}

__global__ __launch_bounds__(256)
void gemm_fin(const u16* __restrict__ A, const u16* __restrict__ Bt,
              void* __restrict__ out, int M, int N, int K, int Ksub) {
    gemm128_body<4>(A, Bt, out, M, N, K, Ksub);
}

// out(=residual x) += sum of 4 bf16 planes; 8 elems/thread
__global__ __launch_bounds__(256)
void fin_reduce(const u16* __restrict__ planes, float* __restrict__ out) {
    const size_t PL = (size_t)4096 * 1024;
    const size_t idx = ((size_t)blockIdx.x * 256 + threadIdx.x) * 8;
    float acc[8] = {0.f, 0.f, 0.f, 0.f, 0.f, 0.f, 0.f, 0.f};
#pragma unroll
    for (int p = 0; p < 4; ++p) {
        ushort4 v0 = *(const ushort4*)(planes + p * PL + idx);
        ushort4 v1 = *(const ushort4*)(planes + p * PL + idx + 4);
        acc[0] += u2f(v0.x); acc[1] += u2f(v0.y); acc[2] += u2f(v0.z); acc[3] += u2f(v0.w);
        acc[4] += u2f(v1.x); acc[5] += u2f(v1.y); acc[6] += u2f(v1.z); acc[7] += u2f(v1.w);
    }
    float4 o0 = *(const float4*)(out + idx);
    float4 o1 = *(const float4*)(out + idx + 4);
    o0.x += acc[0]; o0.y += acc[1]; o0.z += acc[2]; o0.w += acc[3];
    o1.x += acc[4]; o1.y += acc[5]; o1.z += acc[6]; o1.w += acc[7];
    *(float4*)(out + idx) = o0;
    *(float4*)(out + idx + 4) = o1;
}

// ---------- delta GEMM split-K: 128x128 tile, bf16 partial plane per K-half ----------
__global__ __launch_bounds__(256)
void gemm_delta_sk(const u16* __restrict__ A, const u16* __restrict__ Bt,
                   u16* __restrict__ planes, int M, int N, int K, int Ksub) {
    u16* plane = planes + (size_t)blockIdx.y * M * N;
    gemm128_body<0>(A, Bt, plane, M, N, K, Ksub);
}

// ---------- delta reduce: row r -> softplus(p0+p1+bd) rowsum + Bdot cols ----------
__global__ __launch_bounds__(256)
void delta_reduce(const u16* __restrict__ planes, const float* __restrict__ bias,
                  float* __restrict__ dacc, float* __restrict__ Bdotn) {
    const int r = blockIdx.x;            // 0..4095
    const int t = threadIdx.x;           // 0..255  (cols t*8..t*8+7 < 2048)
    const size_t PL = (size_t)4096 * 2176;
    const u16* p0 = planes + (size_t)r * 2176 + t * 8;
    const u16* p1 = p0 + PL;
    ushort4 a0 = *(const ushort4*)p0;
    ushort4 a1 = *(const ushort4*)(p0 + 4);
    ushort4 b0 = *(const ushort4*)p1;
    ushort4 b1 = *(const ushort4*)(p1 + 4);
    float4 c0 = *(const float4*)(bias + t * 8);
    float4 c1 = *(const float4*)(bias + t * 8 + 4);
    float e[8];
    e[0] = u2f(a0.x) + u2f(b0.x) + c0.x;
    e[1] = u2f(a0.y) + u2f(b0.y) + c0.y;
    e[2] = u2f(a0.z) + u2f(b0.z) + c0.z;
    e[3] = u2f(a0.w) + u2f(b0.w) + c0.w;
    e[4] = u2f(a1.x) + u2f(b1.x) + c1.x;
    e[5] = u2f(a1.y) + u2f(b1.y) + c1.y;
    e[6] = u2f(a1.z) + u2f(b1.z) + c1.z;
    e[7] = u2f(a1.w) + u2f(b1.w) + c1.w;
    float sv = 0.f;
#pragma unroll
    for (int i = 0; i < 8; ++i)
        sv += (e[i] > 20.f) ? e[i] : log1pf(expf(e[i]));
#pragma unroll
    for (int off = 32; off > 0; off >>= 1)
        sv += __shfl_down(sv, off, 64);
    __shared__ float wsum[4];
    const int wave = t >> 6, lane = t & 63;
    if (lane == 0) wsum[wave] = sv;
    __syncthreads();
    if (t == 0) dacc[r] = wsum[0] + wsum[1] + wsum[2] + wsum[3];
    if (t < 16) {
        const u16* qp = planes + (size_t)r * 2176 + 2048 + t;
        Bdotn[(size_t)t * 4096 + r] = u2f(*qp) + u2f(*(qp + PL));
    }
}

// ---------- delta GEMM fallback (ws too small): 128M x 64N tile, BK=128 ----------
__global__ __launch_bounds__(256)
void gemm_delta(const u16* __restrict__ A, const u16* __restrict__ Bt,
                float* __restrict__ dacc, const float* __restrict__ bias,
                float* __restrict__ Bdotn, int M, int N, int K) {
    __shared__ u16 As[128 * 128];
    __shared__ u16 Bs[64 * 128];
    int bx, by;
    swz(blockIdx.x, bx, by);
    const int tid = threadIdx.x;
    const int wave = tid >> 6, lane = tid & 63;
    const int row0 = by * 128, col0 = bx * 64;
    const int l16 = lane & 15, q = lane >> 4;
    const int sRow = lane >> 2, sK = (lane & 3) * 8;

    floatx4 acc[2][4];
#pragma unroll
    for (int i = 0; i < 2; ++i)
#pragma unroll
        for (int j = 0; j < 4; ++j) acc[i][j] = (floatx4){0.f, 0.f, 0.f, 0.f};

    const u16* gA = A + (size_t)(row0 + wave * 32 + sRow) * K + sK;
    const u16* gB = Bt + (size_t)(col0 + wave * 16 + sRow) * K + sK;
    u16* lA = As + wave * 1024;
    u16* lB = Bs + wave * 512;
    const int rowb = wave * 32;

    for (int k0 = 0; k0 < K; k0 += 128) {
#pragma unroll
        for (int h = 0; h < 4; ++h) {
            gl_lds16(gA + h * 32, lA + h * 4096);
            gl_lds16(gA + (size_t)16 * K + h * 32, lA + h * 4096 + 512);
            gl_lds16(gB + h * 32, lB + h * 2048);
        }
        gA += 128; gB += 128;
        __syncthreads();
#pragma unroll
        for (int h = 0; h < 4; ++h) {
            bf16x8 af[2], bfr[4];
#pragma unroll
            for (int mi = 0; mi < 2; ++mi)
                af[mi] = *(const bf16x8*)(As + h * 4096 + (rowb + mi * 16 + l16) * 32 + q * 8);
#pragma unroll
            for (int ni = 0; ni < 4; ++ni)
                bfr[ni] = *(const bf16x8*)(Bs + h * 2048 + (ni * 16 + l16) * 32 + q * 8);
#pragma unroll
            for (int mi = 0; mi < 2; ++mi)
#pragma unroll
                for (int ni = 0; ni < 4; ++ni)
                    acc[mi][ni] = __builtin_amdgcn_mfma_f32_16x16x32_bf16(
                        af[mi], bfr[ni], acc[mi][ni], 0, 0, 0);
        }
        __syncthreads();
    }

    const int mB = row0 + rowb;
    const int nB = col0 + l16;
    if (col0 < 2048) {
#pragma unroll
        for (int mi = 0; mi < 2; ++mi) {
#pragma unroll
            for (int rr = 0; rr < 4; ++rr) {
                float sv = 0.f;
#pragma unroll
                for (int ni = 0; ni < 4; ++ni) {
                    float t2 = acc[mi][ni][rr] + bias[nB + ni * 16];
                    sv += (t2 > 20.f) ? t2 : log1pf(expf(t2));
                }
#pragma unroll
                for (int off = 1; off < 16; off <<= 1)
                    sv += __shfl_xor(sv, off, 64);
                if (l16 == 0)
                    atomicAdd(&dacc[mB + mi * 16 + q * 4 + rr], sv);
            }
        }
    } else {
#pragma unroll
        for (int mi = 0; mi < 2; ++mi)
#pragma unroll
            for (int rr = 0; rr < 4; ++rr)
                Bdotn[(size_t)l16 * 4096 + mB + mi * 16 + q * 4 + rr] =
                    acc[mi][0][rr];
    }
}

// ---------- lean conv(K=4)+SiLU, 4 rows/block (1024 blocks) + delta_acc zero ----------
__global__ __launch_bounds__(256) void conv_silu_kernel(const u16* __restrict__ xg,
                                                        const float* __restrict__ conv_w,
                                                        const float* __restrict__ conv_b,
                                                        u16* __restrict__ xsc,
                                                        float* __restrict__ delta_acc) {
    int r0 = blockIdx.x * 4;                  // 4 rows/block; 2048 % 4 == 0
    int l0 = r0 & 2047, bb = r0 >> 11;
    int t = threadIdx.x, d8 = t * 8;
    if (t < 4) delta_acc[r0 + t] = 0.f;       // zero before fallback path's atomics

    ushort4 rw[7][2];                         // rows l0-3 .. l0+3
#pragma unroll
    for (int j = 0; j < 7; ++j) {
        int ls = l0 + j - 3;
        if (ls >= 0) {
            const u16* row = xg + (size_t)((bb << 11) + ls) * 4096 + d8;
            rw[j][0] = *(const ushort4*)row;
            rw[j][1] = *(const ushort4*)(row + 4);
        } else {
            rw[j][0] = (ushort4){0, 0, 0, 0};
            rw[j][1] = (ushort4){0, 0, 0, 0};
        }
    }
    float w[8][4];
#pragma unroll
    for (int j = 0; j < 8; ++j) {
        float4 wv = *(const float4*)(conv_w + (size_t)(d8 + j) * 4);
        w[j][0] = wv.x; w[j][1] = wv.y; w[j][2] = wv.z; w[j][3] = wv.w;
    }
    float cb[8];
    {
        float4 b0 = *(const float4*)(conv_b + d8);
        float4 b1 = *(const float4*)(conv_b + d8 + 4);
        cb[0] = b0.x; cb[1] = b0.y; cb[2] = b0.z; cb[3] = b0.w;
        cb[4] = b1.x; cb[5] = b1.y; cb[6] = b1.z; cb[7] = b1.w;
    }
#pragma unroll
    for (int i = 0; i < 4; ++i) {
        float xs[8];
#pragma unroll
        for (int j = 0; j < 8; ++j) xs[j] = cb[j];
#pragma unroll
        for (int k = 0; k < 4; ++k) {
            ushort4 u0 = rw[i + k][0], u1 = rw[i + k][1];
            xs[0] += w[0][k] * u2f(u0.x); xs[1] += w[1][k] * u2f(u0.y);
            xs[2] += w[2][k] * u2f(u0.z); xs[3] += w[3][k] * u2f(u0.w);
            xs[4] += w[4][k] * u2f(u1.x); xs[5] += w[5][k] * u2f(u1.y);
            xs[6] += w[6][k] * u2f(u1.z); xs[7] += w[7][k] * u2f(u1.w);
        }
        ushort4 o0, o1;
        o0.x = f2u(xs[0] / (1.f + expf(-xs[0])));
        o0.y = f2u(xs[1] / (1.f + expf(-xs[1])));
        o0.z = f2u(xs[2] / (1.f + expf(-xs[2])));
        o0.w = f2u(xs[3] / (1.f + expf(-xs[3])));
        o1.x = f2u(xs[4] / (1.f + expf(-xs[4])));
        o1.y = f2u(xs[5] / (1.f + expf(-xs[5])));
        o1.z = f2u(xs[6] / (1.f + expf(-xs[6])));
        o1.w = f2u(xs[7] / (1.f + expf(-xs[7])));
        u16* orow = xsc + (size_t)(r0 + i) * 2048 + d8;
        *(ushort4*)orow = o0;
        *(ushort4*)(orow + 4) = o1;
    }
}

// ---------- selective scan: 32 chains, 256 threads (4 waves) each ----------
__global__ __launch_bounds__(256) void scan_kernel(const float* __restrict__ delta_acc,
                                                   const float* __restrict__ Bdotn,
                                                   const float* __restrict__ A_log,
                                                   float* __restrict__ hsn) {
    int chain = blockIdx.x;                 // 0..31
    int b = chain >> 4, n = chain & 15;
    int t = threadIdx.x;                    // 0..255
    int wave = t >> 6, lane = t & 63;
    __shared__ float sd[2048], sb[2048];
    __shared__ float wA[4], wB[4];
#pragma unroll
    for (int m = 0; m < 2; ++m) {
        int idx = (m * 256 + t) * 4;
        *(float4*)(sd + idx) = *(const float4*)(delta_acc + b * 2048 + idx);
        *(float4*)(sb + idx) = *(const float4*)(Bdotn + (size_t)n * 4096 + b * 2048 + idx);
    }
    __syncthreads();
    float An = -expf(A_log[n]);
    int base = t * 8;
    float a[8], bb[8];
#pragma unroll
    for (int i = 0; i < 8; ++i) {
        float dl = sd[base + i] * (1.f / 2048.f);
        a[i] = expf(dl * An);
        bb[i] = sb[base + i] * dl;
    }
    float Aacc = 1.f, Bacc = 0.f;
#pragma unroll
    for (int i = 0; i < 8; ++i) {
        Bacc = a[i] * Bacc + bb[i];
        Aacc = a[i] * Aacc;
    }
#pragma unroll
    for (int d = 1; d < 64; d <<= 1) {
        float Ap = __shfl_up(Aacc, d, 64);
        float Bp = __shfl_up(Bacc, d, 64);
        if (lane >= d) {
            Bacc = Aacc * Bp + Bacc;
            Aacc = Aacc * Ap;
        }
    }
    if (lane == 63) { wA[wave] = Aacc; wB[wave] = Bacc; }
    float eA = __shfl_up(Aacc, 1, 64);
    float eB = __shfl_up(Bacc, 1, 64);
    if (lane == 0) { eA = 1.f; eB = 0.f; }
    __syncthreads();
    float pB = 0.f;
#pragma unroll
    for (int w = 0; w < 3; ++w)
        if (w < wave) pB = wA[w] * pB + wB[w];
    float h = eA * pB + eB;
#pragma unroll
    for (int i = 0; i < 8; ++i) {
        h = a[i] * h + bb[i];
        sd[base + i] = h;
    }
    __syncthreads();
#pragma unroll
    for (int m = 0; m < 2; ++m) {
        int idx = (m * 256 + t) * 4;
        *(float4*)(hsn + (size_t)n * 4096 + b * 2048 + idx) = *(const float4*)(sd + idx);
    }
}

// ---------- ymid = (hs·C_mat[d,:] + D_vec*xsc) * silu(gate), bf16 out ----------
// grid (4, 256): block owns d-range [bx*512, +512), rows [by*16, +16). 1024 blocks.
__global__ __launch_bounds__(256) void ymid_kernel(const float* __restrict__ hsn,
                                                   const float* __restrict__ C_mat,
                                                   const float* __restrict__ D_vec,
                                                   const u16* __restrict__ xsc,
                                                   const u16* __restrict__ xg,
                                                   u16* __restrict__ ymid) {
    const int t = threadIdx.x;
    const int d0 = blockIdx.x * 512 + t * 2;
    const int r0 = blockIdx.y * 16;
    __shared__ float hsv[16 * 16];
    {
        int rl = t >> 4, nn = t & 15;          // t covers all 256 entries
        hsv[t] = hsn[(size_t)nn * 4096 + r0 + rl];
    }
    float c0[16], c1[16];
#pragma unroll
    for (int k = 0; k < 4; ++k) {
        float4 v0 = *(const float4*)(C_mat + (size_t)d0 * 16 + k * 4);
        float4 v1 = *(const float4*)(C_mat + (size_t)(d0 + 1) * 16 + k * 4);
        c0[k * 4 + 0] = v0.x; c0[k * 4 + 1] = v0.y; c0[k * 4 + 2] = v0.z; c0[k * 4 + 3] = v0.w;
        c1[k * 4 + 0] = v1.x; c1[k * 4 + 1] = v1.y; c1[k * 4 + 2] = v1.z; c1[k * 4 + 3] = v1.w;
    }
    const float dv0 = D_vec[d0], dv1 = D_vec[d0 + 1];
    __syncthreads();
#pragma unroll 4
    for (int rl = 0; rl < 16; ++rl) {
        const int r = r0 + rl;
        float h0 = 0.f, h1 = 0.f;
#pragma unroll
        for (int nn = 0; nn < 16; ++nn) {
            float hv = hsv[rl * 16 + nn];      // same addr across lanes: broadcast
            h0 += hv * c0[nn];
            h1 += hv * c1[nn];
        }
        unsigned int xv = *(const unsigned int*)(xsc + (size_t)r * 2048 + d0);
        unsigned int gv = *(const unsigned int*)(xg + (size_t)r * 4096 + 2048 + d0);
        float x0 = u2f((u16)(xv & 0xffffu)), x1 = u2f((u16)(xv >> 16));
        float g0 = u2f((u16)(gv & 0xffffu)), g1 = u2f((u16)(gv >> 16));
        float y0 = (h0 + dv0 * x0) * (g0 / (1.f + expf(-g0)));
        float y1 = (h1 + dv1 * x1) * (g1 / (1.f + expf(-g1)));
        unsigned int o = (unsigned int)f2u(y0) | ((unsigned int)f2u(y1) << 16);
        *(unsigned int*)(ymid + (size_t)r * 2048 + d0) = o;
    }
}

extern "C" void kernel_launch(void* const* d_in, const int* in_sizes, int n_in,
                              void* d_out, int out_size, void* d_ws, size_t ws_size,
                              hipStream_t stream) {
    (void)in_sizes; (void)n_in;
    const float* x      = (const float*)d_in[0];
    const float* ln_g   = (const float*)d_in[1];
    const float* ln_b   = (const float*)d_in[2];
    const float* W_in   = (const float*)d_in[3];
    const float* conv_w = (const float*)d_in[4];
    const float* conv_b = (const float*)d_in[5];
    const float* A_log  = (const float*)d_in[6];
    const float* B_mat  = (const float*)d_in[7];
    const float* C_mat  = (const float*)d_in[8];
    const float* D_vec  = (const float*)d_in[9];
    const float* Wd     = (const float*)d_in[10];
    const float* bd     = (const float*)d_in[11];
    const float* W_out  = (const float*)d_in[12];
    float* out = (float*)d_out;

    // ---- workspace layout (time-overlaid) ----
    char* base = (char*)d_ws;
    u16* Wt_in  = (u16*)base;                          // 4096x1024 bf16 (bufA lo)
    u16* h_ln   = (u16*)base + 4096ull * 1024;         // 4096x1024 bf16 (bufA hi)
    u16* ymid   = (u16*)base;                          // 4096x2048 bf16 (reuse bufA post-GEMM1)
    u16* Wt_ext = (u16*)(base + (16ull << 20));        // 2112x2048 bf16 (Wd^T + B_mat + pad)
    u16* Wt_out = (u16*)(base + (25ull << 20));        // 1024x2048 bf16 (4 MiB)
    u16* xg     = (u16*)(base + (29ull << 20));        // 4096x4096 bf16 (32 MiB)
    u16* xsc    = (u16*)(base + (61ull << 20));        // 4096x2048 bf16 (16 MiB)
    float* delta_acc = (float*)(base + (77ull << 20)); // 4096 f32
    float* Bdotn = delta_acc + 4096;                   // [16][4096] f32
    float* hsn   = Bdotn + 16 * 4096;                  // [16][4096] f32
    u16* planes  = (u16*)(base + (78ull << 20));       // delta: 2 x [4096][2176] bf16 = 34 MiB
    u16* fplanes = (u16*)(base + (78ull << 20));       // fin:   4 x [4096][1024] bf16 = 32 MiB (delta planes dead)
    size_t needed = (77ull << 20) + 4096ull * 4 * (1 + 2 * 16);
    size_t needed_sk = (78ull << 20) + 2ull * 4096 * 2176 * 2;   // 112 MiB

    if (needed > ws_size) {
        hipMemsetAsync(d_out, 0x7F, (size_t)out_size * 4, stream);  // finite sentinel
        return;
    }
    const bool use_sk = (ws_size >= needed_sk);

    // 1. prep: transposes (vectorized stores) + B_mat pad + layernorm + out=x
    prep_kernel<<<14848, 256, 0, stream>>>(W_in, Wt_in, Wd, Wt_ext, W_out, Wt_out,
                                           B_mat, x, ln_g, ln_b, h_ln, out);
    // 2. xg = h @ W_in : 256x256 8-phase kernel (T2-swizzled), 256 blocks, 512 threads
    gemm_xg256<<<256, 512, 0, stream>>>(h_ln, Wt_in, xg, 4096, 4096, 1024);
    // 3. conv + silu (+delta_acc zero for fallback), 4 rows/block, 1024 blocks
    conv_silu_kernel<<<1024, 256, 0, stream>>>(xg, conv_w, conv_b, xsc, delta_acc);
    // 4. delta GEMM
    if (use_sk) {
        gemm_delta_sk<<<dim3(544, 2), 256, 0, stream>>>(xsc, Wt_ext, planes,
                                                        4096, 2176, 2048, 1024);
        delta_reduce<<<4096, 256, 0, stream>>>(planes, bd, delta_acc, Bdotn);
    } else {
        gemm_delta<<<1056, 256, 0, stream>>>(xsc, Wt_ext, delta_acc, bd, Bdotn,
                                             4096, 2112, 2048);
    }
    // 5. selective scan: 32 chains x 256 threads
    scan_kernel<<<32, 256, 0, stream>>>(delta_acc, Bdotn, A_log, hsn);
    // 6. ymid (into bufA; h_ln/Wt_in dead): C-in-registers, 16 rows/block, 1024 blocks
    ymid_kernel<<<dim3(4, 256), 256, 0, stream>>>(hsn, C_mat, D_vec, xsc, xg, ymid);
    // 7. out += ymid @ W_out
    if (use_sk) {
        // 256x256 8-phase split-K=4 into bf16 planes: (64,4) = 256 blocks (1/CU)
        gemm_fin256<<<dim3(64, 4), 512, 0, stream>>>(ymid, Wt_out, fplanes,
                                                     4096, 1024, 2048, 512);
        fin_reduce<<<2048, 256, 0, stream>>>(fplanes, out);
    } else {
        gemm_fin<<<dim3(256, 2), 256, 0, stream>>>(ymid, Wt_out, out, 4096, 1024, 2048, 1024);
    }
}

// Round 11
// 312.212 us; speedup vs baseline: 1.0087x; 1.0087x over previous
//
#include <hip/hip_runtime.h>
#include <cstdint>
#include <cstddef>

typedef unsigned short u16;
typedef __attribute__((ext_vector_type(4))) float floatx4;
typedef __attribute__((ext_vector_type(8))) __bf16 bf16x8;

// ---------- bf16 helpers ----------
__device__ __forceinline__ float u2f(u16 u) {
    union { unsigned int i; float f; } x;
    x.i = ((unsigned int)u) << 16;
    return x.f;
}
__device__ __forceinline__ u16 f2u(float f) {
    union { float f; unsigned int i; } x;
    x.f = f;
    unsigned int r = x.i + 0x7fffu + ((x.i >> 16) & 1u);   // RNE
    return (u16)(r >> 16);
}

// ---------- XCD-aware swizzle: bid -> (x,y); XCD k owns y-strip [4k,4k+4), x-major ----------
__device__ __forceinline__ void swz(int bid, int& x, int& y) {
    int xcd = bid & 7;
    int lid = bid >> 3;
    x = lid >> 2;
    y = xcd * 4 + (lid & 3);
}

// ---------- prep: 3 weight transposes + B_mat cast-copy/pad + layernorm(+out=x) ----------
__device__ __forceinline__ void tr_tile(const float* __restrict__ in, u16* __restrict__ out,
                                        int K, int N, int bx, int by, float* tile /*32x33*/) {
    int n0 = bx * 32, k0 = by * 32;
    int t = threadIdx.x;
    int r = t >> 3, c4 = (t & 7) * 4;          // input row k0+r, cols n0+c4..+3
    float4 v = *(const float4*)(in + (size_t)(k0 + r) * N + n0 + c4);
    tile[r * 33 + c4 + 0] = v.x;
    tile[r * 33 + c4 + 1] = v.y;
    tile[r * 33 + c4 + 2] = v.z;
    tile[r * 33 + c4 + 3] = v.w;
    __syncthreads();
    int n = t >> 3, kg = (t & 7) * 4;          // output row n0+n, k cols k0+kg..+3
    ushort4 o;
    o.x = f2u(tile[(kg + 0) * 33 + n]);
    o.y = f2u(tile[(kg + 1) * 33 + n]);
    o.z = f2u(tile[(kg + 2) * 33 + n]);
    o.w = f2u(tile[(kg + 3) * 33 + n]);
    *(ushort4*)(out + (size_t)(n0 + n) * K + k0 + kg) = o;
}

// blocks: [0,4096) W_in tr; [4096,8192) Wd tr (rows 0..2047 of Wt_ext);
//         [8192,10240) W_out tr; [10240,14336) layernorm; [14336,14848) B_mat copy+pad (64 rows)
__global__ __launch_bounds__(256)
void prep_kernel(const float* __restrict__ W_in, u16* __restrict__ Wt_in,
                 const float* __restrict__ Wd, u16* __restrict__ Wt_ext,
                 const float* __restrict__ W_out, u16* __restrict__ Wt_out,
                 const float* __restrict__ B_mat,
                 const float* __restrict__ x, const float* __restrict__ gamma,
                 const float* __restrict__ beta, u16* __restrict__ h,
                 float* __restrict__ out) {
    __shared__ float tile[32 * 33];
    int blk = blockIdx.x, t = threadIdx.x;
    if (blk < 4096) {
        tr_tile(W_in, Wt_in, 1024, 4096, blk & 127, blk >> 7, tile);
    } else if (blk < 8192) {
        int b2 = blk - 4096;
        tr_tile(Wd, Wt_ext, 2048, 2048, b2 & 63, b2 >> 6, tile);
    } else if (blk < 10240) {
        int b3 = blk - 8192;
        tr_tile(W_out, Wt_out, 2048, 1024, b3 & 31, b3 >> 5, tile);
    } else if (blk < 14336) {
        int r = blk - 10240;
        const float4* xr = (const float4*)(x + (size_t)r * 1024);
        float4 xv = xr[t];
        ((float4*)(out + (size_t)r * 1024))[t] = xv;   // residual base (fin path adds)
        float s = xv.x + xv.y + xv.z + xv.w;
        float ss = xv.x * xv.x + xv.y * xv.y + xv.z * xv.z + xv.w * xv.w;
#pragma unroll
        for (int off = 32; off > 0; off >>= 1) {
            s += __shfl_down(s, off, 64);
            ss += __shfl_down(ss, off, 64);
        }
        __shared__ float rs[4], rss[4], mu_s, ri_s;
        int wave = t >> 6, lane = t & 63;
        if (lane == 0) { rs[wave] = s; rss[wave] = ss; }
        __syncthreads();
        if (t == 0) {
            float S = rs[0] + rs[1] + rs[2] + rs[3];
            float SS = rss[0] + rss[1] + rss[2] + rss[3];
            float mu = S * (1.f / 1024.f);
            float var = SS * (1.f / 1024.f) - mu * mu;
            mu_s = mu;
            ri_s = rsqrtf(fmaxf(var, 0.f) + 1e-5f);
        }
        __syncthreads();
        float mu = mu_s, ri = ri_s;
        float4 gv = ((const float4*)gamma)[t];
        float4 bv = ((const float4*)beta)[t];
        ushort4 o;
        o.x = f2u((xv.x - mu) * ri * gv.x + bv.x);
        o.y = f2u((xv.y - mu) * ri * gv.y + bv.y);
        o.z = f2u((xv.z - mu) * ri * gv.z + bv.z);
        o.w = f2u((xv.w - mu) * ri * gv.w + bv.w);
        ((ushort4*)(h + (size_t)r * 1024))[t] = o;
    } else {
        // Wt_ext rows 2048..2111: first 16 = B_mat (bf16 cast), rest zero pad
        int idx = (blk - 14336) * 256 + t;         // 0..131071
        int row = 2048 + (idx >> 11), col = idx & 2047;
        u16 v = (row < 2064) ? f2u(B_mat[(size_t)(row - 2048) * 2048 + col]) : (u16)0;
        Wt_ext[(size_t)row * 2048 + col] = v;
    }
}

__device__ __forceinline__ void gl_lds16(const u16* g, u16* l) {
    __builtin_amdgcn_global_load_lds(
        (const __attribute__((address_space(1))) void*)g,
        (__attribute__((address_space(3))) void*)l, 16, 0, 0);
}

// ================== 256x256 8-phase GEMM body (T2 col16-swizzled LDS) ==============
// 512 threads = 8 waves (wr=wid>>2 in {0,1}, wc=wid&3 in {0..3}); per-wave out 128x64.
// LDS 128 KB: As/Bs[2 bufs][2 kk-pages][256 rows][32 cols] bf16.
// T2 swizzle: LDS(row,c16) holds global(row, c16 ^ s(row)), s(row)=(row>>2)&3.
template <int CB, int NB>
__device__ __forceinline__
void ktile256(u16 (&As)[2][16384], u16 (&Bs)[2][16384],
              const u16* __restrict__ gA, const u16* __restrict__ gB,
              int kt, bool doStage, int K,
              int w, int wr, int wc, int l16, int qsw,
              floatx4 (&acc)[8][4]) {
    asm volatile("s_waitcnt vmcnt(0)" ::: "memory");
    __builtin_amdgcn_s_barrier();
    asm volatile("" ::: "memory");
    bf16x8 af[4][2], bfr[4][2];
    const int aBase = wr * 128, bBase = wc * 64;
    // ---- phase 0: read af(mi 0-3) + bfr(ni 0-1); stage A(kt+1) ----
#pragma unroll
    for (int i = 0; i < 4; ++i)
#pragma unroll
        for (int h = 0; h < 2; ++h)
            af[i][h] = *(const bf16x8*)&As[CB][h * 8192 + (aBase + i * 16 + l16) * 32 + qsw * 8];
#pragma unroll
    for (int j = 0; j < 2; ++j)
#pragma unroll
        for (int h = 0; h < 2; ++h)
            bfr[j][h] = *(const bf16x8*)&Bs[CB][h * 8192 + (bBase + j * 16 + l16) * 32 + qsw * 8];
    if (doStage) {
        const u16* p = gA + (size_t)(kt + 1) * 64;
#pragma unroll
        for (int h = 0; h < 2; ++h) {
            gl_lds16(p + h * 32,                  &As[NB][h * 8192 + w * 1024]);
            gl_lds16(p + (size_t)16 * K + h * 32, &As[NB][h * 8192 + w * 1024 + 512]);
        }
    }
    __builtin_amdgcn_s_barrier();
    __builtin_amdgcn_s_setprio(1);
#pragma unroll
    for (int i = 0; i < 4; ++i)
#pragma unroll
        for (int j = 0; j < 2; ++j)
#pragma unroll
            for (int h = 0; h < 2; ++h)
                acc[i][j] = __builtin_amdgcn_mfma_f32_16x16x32_bf16(af[i][h], bfr[j][h], acc[i][j], 0, 0, 0);
    __builtin_amdgcn_s_setprio(0);
    __builtin_amdgcn_s_barrier();
    // ---- phase 1: read bfr(ni 2-3); stage B(kt+1) ----
#pragma unroll
    for (int j = 2; j < 4; ++j)
#pragma unroll
        for (int h = 0; h < 2; ++h)
            bfr[j][h] = *(const bf16x8*)&Bs[CB][h * 8192 + (bBase + j * 16 + l16) * 32 + qsw * 8];
    if (doStage) {
        const u16* p = gB + (size_t)(kt + 1) * 64;
#pragma unroll
        for (int h = 0; h < 2; ++h) {
            gl_lds16(p + h * 32,                  &Bs[NB][h * 8192 + w * 1024]);
            gl_lds16(p + (size_t)16 * K + h * 32, &Bs[NB][h * 8192 + w * 1024 + 512]);
        }
    }
    __builtin_amdgcn_s_barrier();
    __builtin_amdgcn_s_setprio(1);
#pragma unroll
    for (int i = 0; i < 4; ++i)
#pragma unroll
        for (int j = 2; j < 4; ++j)
#pragma unroll
            for (int h = 0; h < 2; ++h)
                acc[i][j] = __builtin_amdgcn_mfma_f32_16x16x32_bf16(af[i][h], bfr[j][h], acc[i][j], 0, 0, 0);
    __builtin_amdgcn_s_setprio(0);
    __builtin_amdgcn_s_barrier();
    // ---- phase 2: read af(mi 4-7); mfma mi4-7 x ni0-1 ----
#pragma unroll
    for (int i = 0; i < 4; ++i)
#pragma unroll
        for (int h = 0; h < 2; ++h)
            af[i][h] = *(const bf16x8*)&As[CB][h * 8192 + (aBase + (4 + i) * 16 + l16) * 32 + qsw * 8];
    __builtin_amdgcn_s_barrier();
    __builtin_amdgcn_s_setprio(1);
#pragma unroll
    for (int i = 0; i < 4; ++i)
#pragma unroll
        for (int j = 0; j < 2; ++j)
#pragma unroll
            for (int h = 0; h < 2; ++h)
                acc[4 + i][j] = __builtin_amdgcn_mfma_f32_16x16x32_bf16(af[i][h], bfr[j][h], acc[4 + i][j], 0, 0, 0);
    __builtin_amdgcn_s_setprio(0);
    __builtin_amdgcn_s_barrier();
    // ---- phase 3: mfma mi4-7 x ni2-3 (no reads) ----
    __builtin_amdgcn_s_setprio(1);
#pragma unroll
    for (int i = 0; i < 4; ++i)
#pragma unroll
        for (int j = 2; j < 4; ++j)
#pragma unroll
            for (int h = 0; h < 2; ++h)
                acc[4 + i][j] = __builtin_amdgcn_mfma_f32_16x16x32_bf16(af[i][h], bfr[j][h], acc[4 + i][j], 0, 0, 0);
    __builtin_amdgcn_s_setprio(0);
    __builtin_amdgcn_s_barrier();
}

// shared 256x256 body; koff/Ksub for split-K; out = bf16 plane of stride N
__device__ __forceinline__
void gemm256_body(const u16* __restrict__ A, const u16* __restrict__ Bt,
                  u16* __restrict__ out, int M, int N, int K,
                  int koff, int Ksub, int bx, int by) {
    __shared__ u16 As[2][16384];   // 64 KB
    __shared__ u16 Bs[2][16384];   // 64 KB
    const int tid = threadIdx.x;
    const int w = tid >> 6, lane = tid & 63;
    const int wr = w >> 2, wc = w & 3;
    const int row0 = by * 256, col0 = bx * 256;
    const int l16 = lane & 15, q = lane >> 4;
    const int sRow = lane >> 2;
    const int sKsw = ((lane & 3) ^ ((lane >> 4) & 3)) * 8;   // T2 source swizzle
    const int qsw = q ^ ((l16 >> 2) & 3);                    // T2 read swizzle

    floatx4 acc[8][4];
#pragma unroll
    for (int i = 0; i < 8; ++i)
#pragma unroll
        for (int j = 0; j < 4; ++j) acc[i][j] = (floatx4){0.f, 0.f, 0.f, 0.f};

    const u16* gA = A + (size_t)(row0 + w * 32 + sRow) * K + koff + sKsw;
    const u16* gB = Bt + (size_t)(col0 + w * 32 + sRow) * K + koff + sKsw;

    // prologue: stage K-tile 0 into buf0 (8 loads/thread)
#pragma unroll
    for (int h = 0; h < 2; ++h) {
        gl_lds16(gA + h * 32,                  &As[0][h * 8192 + w * 1024]);
        gl_lds16(gA + (size_t)16 * K + h * 32, &As[0][h * 8192 + w * 1024 + 512]);
        gl_lds16(gB + h * 32,                  &Bs[0][h * 8192 + w * 1024]);
        gl_lds16(gB + (size_t)16 * K + h * 32, &Bs[0][h * 8192 + w * 1024 + 512]);
    }

    const int nkt = Ksub >> 6;   // must be even
    for (int t2 = 0; t2 < nkt; t2 += 2) {
        ktile256<0, 1>(As, Bs, gA, gB, t2, true, K, w, wr, wc, l16, qsw, acc);
        ktile256<1, 0>(As, Bs, gA, gB, t2 + 1, (t2 + 2) < nkt, K, w, wr, wc, l16, qsw, acc);
    }

    const int mB = row0 + wr * 128;
    const int nB = col0 + wc * 64 + l16;
#pragma unroll
    for (int mi = 0; mi < 8; ++mi)
#pragma unroll
        for (int ni = 0; ni < 4; ++ni)
#pragma unroll
            for (int rr = 0; rr < 4; ++rr)
                out[(size_t)(mB + mi * 16 + q * 4 + rr) * N + nB + ni * 16] =
                    f2u(acc[mi][ni][rr]);
}

// xg = h_ln @ Wt_in : M=N=4096, K=1024; grid 256 = 16x16 tiles, 1 block/CU.
__global__ __launch_bounds__(512, 2)
void gemm_xg256(const u16* __restrict__ A, const u16* __restrict__ Bt,
                u16* __restrict__ out, int M, int N, int K) {
    const int bid = blockIdx.x;
    const int xcd = bid & 7, lid = bid >> 3;       // per-XCD 2-row y-strips
    const int by = xcd * 2 + (lid & 1), bx = lid >> 1;
    gemm256_body(A, Bt, out, M, N, K, 0, K, bx, by);
}

// fin split-K=4 into bf16 planes via 256x256 8-phase body: grid (64,4) = 256 blocks (1/CU)
__global__ __launch_bounds__(512, 2)
void gemm_fin256(const u16* __restrict__ A, const u16* __restrict__ Bt,
                 u16* __restrict__ planes, int M, int N, int K, int Ksub) {
    u16* plane = planes + (size_t)blockIdx.y * M * N;
    const int bid = blockIdx.x;                    // 0..63
    const int bx = bid >> 4, by = bid & 15;        // 4 N-tiles x 16 M-tiles
    gemm256_body(A, Bt, plane, M, N, K, blockIdx.y * Ksub, Ksub, bx, by);
}

// delta main (cols 0..2047) split-K=2 into bf16 planes [2][4096][2048]:
// grid (128,2) = 256 blocks (1/CU). Bdot cols handled by bdot_kernel.
__global__ __launch_bounds__(512, 2)
void gemm_delta256(const u16* __restrict__ A, const u16* __restrict__ Bt,
                   u16* __restrict__ planes, int M, int N, int K, int Ksub) {
    u16* plane = planes + (size_t)blockIdx.y * M * N;   // N = 2048
    const int bid = blockIdx.x;                    // 0..127
    const int xcd = bid & 7, lid = bid >> 3;       // lid 0..15
    const int by = xcd * 2 + (lid & 1), bx = lid >> 1;   // by 0..15, bx 0..7
    gemm256_body(A, Bt, plane, M, N, K, blockIdx.y * Ksub, Ksub, bx, by);
}

// Bdotn[n][r] = sum_k xsc[r,k]*B[n,k], f32 direct (full K, no split).
// 64 blocks x 4 waves; wave owns 16 rows x 16 n; 64 MFMA over K=2048.
// Fragment layouts identical to gemm128 body (A row=l16,k=q*8; B col=l16,k=q*8;
// C row=q*4+rr, col=l16).
__global__ __launch_bounds__(256)
void bdot_kernel(const u16* __restrict__ xsc, const u16* __restrict__ B16,
                 float* __restrict__ Bdotn) {
    const int w = threadIdx.x >> 6, lane = threadIdx.x & 63;
    const int r0 = blockIdx.x * 64 + w * 16;
    const int l16 = lane & 15, q = lane >> 4;
    floatx4 acc = (floatx4){0.f, 0.f, 0.f, 0.f};
    const u16* pA = xsc + (size_t)(r0 + l16) * 2048 + q * 8;
    const u16* pB = B16 + (size_t)l16 * 2048 + q * 8;
    for (int kt = 0; kt < 2048; kt += 32) {
        bf16x8 a = *(const bf16x8*)(pA + kt);
        bf16x8 b = *(const bf16x8*)(pB + kt);
        acc = __builtin_amdgcn_mfma_f32_16x16x32_bf16(a, b, acc, 0, 0, 0);
    }
#pragma unroll
    for (int rr = 0; rr < 4; ++rr)
        Bdotn[(size_t)l16 * 4096 + r0 + q * 4 + rr] = acc[rr];
}

// ---------- 128x128 tile GEMM, BK=64, 4 waves x (4x4 frags), 32 KB LDS ----------
// EPI 0: bf16 store;  EPI 4: atomicAdd f32 (fallback fin)
template <int EPI>
__device__ __forceinline__
void gemm128_body(const u16* __restrict__ A, const u16* __restrict__ Bt,
                  void* __restrict__ out, int M, int N, int K, int Ksub) {
    __shared__ u16 As[128 * 64];
    __shared__ u16 Bs[128 * 64];
    int bx, by;
    swz(blockIdx.x, bx, by);
    const int tid = threadIdx.x;
    const int wave = tid >> 6, lane = tid & 63;
    const int row0 = by * 128, col0 = bx * 128;
    const int koff = blockIdx.y * Ksub;
    const int l16 = lane & 15, q = lane >> 4;
    const int sRow = lane >> 2, sK = (lane & 3) * 8;

    floatx4 acc[4][4];
#pragma unroll
    for (int i = 0; i < 4; ++i)
#pragma unroll
        for (int j = 0; j < 4; ++j) acc[i][j] = (floatx4){0.f, 0.f, 0.f, 0.f};

    const u16* gA = A + (size_t)(row0 + wave * 32 + sRow) * K + koff + sK;
    const u16* gB = Bt + (size_t)(col0 + wave * 32 + sRow) * K + koff + sK;
    u16* lA = As + wave * 1024;
    u16* lB = Bs + wave * 1024;
    const int rowb = (wave >> 1) * 64, colb = (wave & 1) * 64;

    for (int k0 = 0; k0 < Ksub; k0 += 64) {
#pragma unroll
        for (int h = 0; h < 2; ++h) {
            gl_lds16(gA + h * 32, lA + h * 4096);
            gl_lds16(gA + (size_t)16 * K + h * 32, lA + h * 4096 + 512);
            gl_lds16(gB + h * 32, lB + h * 4096);
            gl_lds16(gB + (size_t)16 * K + h * 32, lB + h * 4096 + 512);
        }
        gA += 64; gB += 64;
        __syncthreads();
#pragma unroll
        for (int h = 0; h < 2; ++h) {
            bf16x8 af[4], bfr[4];
#pragma unroll
            for (int mi = 0; mi < 4; ++mi)
                af[mi] = *(const bf16x8*)(As + h * 4096 + (rowb + mi * 16 + l16) * 32 + q * 8);
#pragma unroll
            for (int ni = 0; ni < 4; ++ni)
                bfr[ni] = *(const bf16x8*)(Bs + h * 4096 + (colb + ni * 16 + l16) * 32 + q * 8);
#pragma unroll
            for (int mi = 0; mi < 4; ++mi)
#pragma unroll
                for (int ni = 0; ni < 4; ++ni)
                    acc[mi][ni] = __builtin_amdgcn_mfma_f32_16x16x32_bf16(
                        af[mi], bfr[ni], acc[mi][ni], 0, 0, 0);
        }
        __syncthreads();
    }

    const int mB = row0 + rowb;
    const int nB = col0 + colb + l16;
    if constexpr (EPI == 0) {
        u16* o = (u16*)out;
#pragma unroll
        for (int mi = 0; mi < 4; ++mi)
#pragma unroll
            for (int ni = 0; ni < 4; ++ni)
#pragma unroll
                for (int rr = 0; rr < 4; ++rr)
                    o[(size_t)(mB + mi * 16 + q * 4 + rr) * N + nB + ni * 16] =
                        f2u(acc[mi][ni][rr]);
    } else {
        float* C = (float*)out;
#pragma unroll
        for (int mi = 0; mi < 4; ++mi)
#pragma unroll
            for (int ni = 0; ni < 4; ++ni)
#pragma unroll
                for (int rr = 0; rr < 4; ++rr)
                    atomicAdd(&C[(size_t)(mB + mi * 16 + q * 4 + rr) * N + nB + ni * 16],
                              acc[mi][ni][rr]);
    }
}

__global__ __launch_bounds__(256)
void gemm_fin(const u16* __restrict__ A, const u16* __restrict__ Bt,
              void* __restrict__ out, int M, int N, int K, int Ksub) {
    gemm128_body<4>(A, Bt, out, M, N, K, Ksub);
}

// out(=residual x) += sum of 4 bf16 planes; 8 elems/thread
__global__ __launch_bounds__(256)
void fin_reduce(const u16* __restrict__ planes, float* __restrict__ out) {
    const size_t PL = (size_t)4096 * 1024;
    const size_t idx = ((size_t)blockIdx.x * 256 + threadIdx.x) * 8;
    float acc[8] = {0.f, 0.f, 0.f, 0.f, 0.f, 0.f, 0.f, 0.f};
#pragma unroll
    for (int p = 0; p < 4; ++p) {
        ushort4 v0 = *(const ushort4*)(planes + p * PL + idx);
        ushort4 v1 = *(const ushort4*)(planes + p * PL + idx + 4);
        acc[0] += u2f(v0.x); acc[1] += u2f(v0.y); acc[2] += u2f(v0.z); acc[3] += u2f(v0.w);
        acc[4] += u2f(v1.x); acc[5] += u2f(v1.y); acc[6] += u2f(v1.z); acc[7] += u2f(v1.w);
    }
    float4 o0 = *(const float4*)(out + idx);
    float4 o1 = *(const float4*)(out + idx + 4);
    o0.x += acc[0]; o0.y += acc[1]; o0.z += acc[2]; o0.w += acc[3];
    o1.x += acc[4]; o1.y += acc[5]; o1.z += acc[6]; o1.w += acc[7];
    *(float4*)(out + idx) = o0;
    *(float4*)(out + idx + 4) = o1;
}

// ---------- delta reduce: row r -> softplus(p0+p1+bd) rowsum (planes stride 2048) ----------
__global__ __launch_bounds__(256)
void delta_reduce(const u16* __restrict__ planes, const float* __restrict__ bias,
                  float* __restrict__ dacc) {
    const int r = blockIdx.x;            // 0..4095
    const int t = threadIdx.x;           // 0..255  (cols t*8..t*8+7 < 2048)
    const size_t PL = (size_t)4096 * 2048;
    const u16* p0 = planes + (size_t)r * 2048 + t * 8;
    const u16* p1 = p0 + PL;
    ushort4 a0 = *(const ushort4*)p0;
    ushort4 a1 = *(const ushort4*)(p0 + 4);
    ushort4 b0 = *(const ushort4*)p1;
    ushort4 b1 = *(const ushort4*)(p1 + 4);
    float4 c0 = *(const float4*)(bias + t * 8);
    float4 c1 = *(const float4*)(bias + t * 8 + 4);
    float e[8];
    e[0] = u2f(a0.x) + u2f(b0.x) + c0.x;
    e[1] = u2f(a0.y) + u2f(b0.y) + c0.y;
    e[2] = u2f(a0.z) + u2f(b0.z) + c0.z;
    e[3] = u2f(a0.w) + u2f(b0.w) + c0.w;
    e[4] = u2f(a1.x) + u2f(b1.x) + c1.x;
    e[5] = u2f(a1.y) + u2f(b1.y) + c1.y;
    e[6] = u2f(a1.z) + u2f(b1.z) + c1.z;
    e[7] = u2f(a1.w) + u2f(b1.w) + c1.w;
    float sv = 0.f;
#pragma unroll
    for (int i = 0; i < 8; ++i)
        sv += (e[i] > 20.f) ? e[i] : log1pf(expf(e[i]));
#pragma unroll
    for (int off = 32; off > 0; off >>= 1)
        sv += __shfl_down(sv, off, 64);
    __shared__ float wsum[4];
    const int wave = t >> 6, lane = t & 63;
    if (lane == 0) wsum[wave] = sv;
    __syncthreads();
    if (t == 0) dacc[r] = wsum[0] + wsum[1] + wsum[2] + wsum[3];
}

// ---------- delta GEMM fallback (ws too small): 128M x 64N tile, BK=128 ----------
__global__ __launch_bounds__(256)
void gemm_delta(const u16* __restrict__ A, const u16* __restrict__ Bt,
                float* __restrict__ dacc, const float* __restrict__ bias,
                float* __restrict__ Bdotn, int M, int N, int K) {
    __shared__ u16 As[128 * 128];
    __shared__ u16 Bs[64 * 128];
    int bx, by;
    swz(blockIdx.x, bx, by);
    const int tid = threadIdx.x;
    const int wave = tid >> 6, lane = tid & 63;
    const int row0 = by * 128, col0 = bx * 64;
    const int l16 = lane & 15, q = lane >> 4;
    const int sRow = lane >> 2, sK = (lane & 3) * 8;

    floatx4 acc[2][4];
#pragma unroll
    for (int i = 0; i < 2; ++i)
#pragma unroll
        for (int j = 0; j < 4; ++j) acc[i][j] = (floatx4){0.f, 0.f, 0.f, 0.f};

    const u16* gA = A + (size_t)(row0 + wave * 32 + sRow) * K + sK;
    const u16* gB = Bt + (size_t)(col0 + wave * 16 + sRow) * K + sK;
    u16* lA = As + wave * 1024;
    u16* lB = Bs + wave * 512;
    const int rowb = wave * 32;

    for (int k0 = 0; k0 < K; k0 += 128) {
#pragma unroll
        for (int h = 0; h < 4; ++h) {
            gl_lds16(gA + h * 32, lA + h * 4096);
            gl_lds16(gA + (size_t)16 * K + h * 32, lA + h * 4096 + 512);
            gl_lds16(gB + h * 32, lB + h * 2048);
        }
        gA += 128; gB += 128;
        __syncthreads();
#pragma unroll
        for (int h = 0; h < 4; ++h) {
            bf16x8 af[2], bfr[4];
#pragma unroll
            for (int mi = 0; mi < 2; ++mi)
                af[mi] = *(const bf16x8*)(As + h * 4096 + (rowb + mi * 16 + l16) * 32 + q * 8);
#pragma unroll
            for (int ni = 0; ni < 4; ++ni)
                bfr[ni] = *(const bf16x8*)(Bs + h * 2048 + (ni * 16 + l16) * 32 + q * 8);
#pragma unroll
            for (int mi = 0; mi < 2; ++mi)
#pragma unroll
                for (int ni = 0; ni < 4; ++ni)
                    acc[mi][ni] = __builtin_amdgcn_mfma_f32_16x16x32_bf16(
                        af[mi], bfr[ni], acc[mi][ni], 0, 0, 0);
        }
        __syncthreads();
    }

    const int mB = row0 + rowb;
    const int nB = col0 + l16;
    if (col0 < 2048) {
#pragma unroll
        for (int mi = 0; mi < 2; ++mi) {
#pragma unroll
            for (int rr = 0; rr < 4; ++rr) {
                float sv = 0.f;
#pragma unroll
                for (int ni = 0; ni < 4; ++ni) {
                    float t2 = acc[mi][ni][rr] + bias[nB + ni * 16];
                    sv += (t2 > 20.f) ? t2 : log1pf(expf(t2));
                }
#pragma unroll
                for (int off = 1; off < 16; off <<= 1)
                    sv += __shfl_xor(sv, off, 64);
                if (l16 == 0)
                    atomicAdd(&dacc[mB + mi * 16 + q * 4 + rr], sv);
            }
        }
    } else {
#pragma unroll
        for (int mi = 0; mi < 2; ++mi)
#pragma unroll
            for (int rr = 0; rr < 4; ++rr)
                Bdotn[(size_t)l16 * 4096 + mB + mi * 16 + q * 4 + rr] =
                    acc[mi][0][rr];
    }
}

// ---------- lean conv(K=4)+SiLU, 4 rows/block (1024 blocks) + delta_acc zero ----------
__global__ __launch_bounds__(256) void conv_silu_kernel(const u16* __restrict__ xg,
                                                        const float* __restrict__ conv_w,
                                                        const float* __restrict__ conv_b,
                                                        u16* __restrict__ xsc,
                                                        float* __restrict__ delta_acc) {
    int r0 = blockIdx.x * 4;                  // 4 rows/block; 2048 % 4 == 0
    int l0 = r0 & 2047, bb = r0 >> 11;
    int t = threadIdx.x, d8 = t * 8;
    if (t < 4) delta_acc[r0 + t] = 0.f;       // zero before fallback path's atomics

    ushort4 rw[7][2];                         // rows l0-3 .. l0+3
#pragma unroll
    for (int j = 0; j < 7; ++j) {
        int ls = l0 + j - 3;
        if (ls >= 0) {
            const u16* row = xg + (size_t)((bb << 11) + ls) * 4096 + d8;
            rw[j][0] = *(const ushort4*)row;
            rw[j][1] = *(const ushort4*)(row + 4);
        } else {
            rw[j][0] = (ushort4){0, 0, 0, 0};
            rw[j][1] = (ushort4){0, 0, 0, 0};
        }
    }
    float w[8][4];
#pragma unroll
    for (int j = 0; j < 8; ++j) {
        float4 wv = *(const float4*)(conv_w + (size_t)(d8 + j) * 4);
        w[j][0] = wv.x; w[j][1] = wv.y; w[j][2] = wv.z; w[j][3] = wv.w;
    }
    float cb[8];
    {
        float4 b0 = *(const float4*)(conv_b + d8);
        float4 b1 = *(const float4*)(conv_b + d8 + 4);
        cb[0] = b0.x; cb[1] = b0.y; cb[2] = b0.z; cb[3] = b0.w;
        cb[4] = b1.x; cb[5] = b1.y; cb[6] = b1.z; cb[7] = b1.w;
    }
#pragma unroll
    for (int i = 0; i < 4; ++i) {
        float xs[8];
#pragma unroll
        for (int j = 0; j < 8; ++j) xs[j] = cb[j];
#pragma unroll
        for (int k = 0; k < 4; ++k) {
            ushort4 u0 = rw[i + k][0], u1 = rw[i + k][1];
            xs[0] += w[0][k] * u2f(u0.x); xs[1] += w[1][k] * u2f(u0.y);
            xs[2] += w[2][k] * u2f(u0.z); xs[3] += w[3][k] * u2f(u0.w);
            xs[4] += w[4][k] * u2f(u1.x); xs[5] += w[5][k] * u2f(u1.y);
            xs[6] += w[6][k] * u2f(u1.z); xs[7] += w[7][k] * u2f(u1.w);
        }
        ushort4 o0, o1;
        o0.x = f2u(xs[0] / (1.f + expf(-xs[0])));
        o0.y = f2u(xs[1] / (1.f + expf(-xs[1])));
        o0.z = f2u(xs[2] / (1.f + expf(-xs[2])));
        o0.w = f2u(xs[3] / (1.f + expf(-xs[3])));
        o1.x = f2u(xs[4] / (1.f + expf(-xs[4])));
        o1.y = f2u(xs[5] / (1.f + expf(-xs[5])));
        o1.z = f2u(xs[6] / (1.f + expf(-xs[6])));
        o1.w = f2u(xs[7] / (1.f + expf(-xs[7])));
        u16* orow = xsc + (size_t)(r0 + i) * 2048 + d8;
        *(ushort4*)orow = o0;
        *(ushort4*)(orow + 4) = o1;
    }
}

// ---------- selective scan: 32 chains, 256 threads (4 waves) each ----------
__global__ __launch_bounds__(256) void scan_kernel(const float* __restrict__ delta_acc,
                                                   const float* __restrict__ Bdotn,
                                                   const float* __restrict__ A_log,
                                                   float* __restrict__ hsn) {
    int chain = blockIdx.x;                 // 0..31
    int b = chain >> 4, n = chain & 15;
    int t = threadIdx.x;                    // 0..255
    int wave = t >> 6, lane = t & 63;
    __shared__ float sd[2048], sb[2048];
    __shared__ float wA[4], wB[4];
#pragma unroll
    for (int m = 0; m < 2; ++m) {
        int idx = (m * 256 + t) * 4;
        *(float4*)(sd + idx) = *(const float4*)(delta_acc + b * 2048 + idx);
        *(float4*)(sb + idx) = *(const float4*)(Bdotn + (size_t)n * 4096 + b * 2048 + idx);
    }
    __syncthreads();
    float An = -expf(A_log[n]);
    int base = t * 8;
    float a[8], bb[8];
#pragma unroll
    for (int i = 0; i < 8; ++i) {
        float dl = sd[base + i] * (1.f / 2048.f);
        a[i] = expf(dl * An);
        bb[i] = sb[base + i] * dl;
    }
    float Aacc = 1.f, Bacc = 0.f;
#pragma unroll
    for (int i = 0; i < 8; ++i) {
        Bacc = a[i] * Bacc + bb[i];
        Aacc = a[i] * Aacc;
    }
#pragma unroll
    for (int d = 1; d < 64; d <<= 1) {
        float Ap = __shfl_up(Aacc, d, 64);
        float Bp = __shfl_up(Bacc, d, 64);
        if (lane >= d) {
            Bacc = Aacc * Bp + Bacc;
            Aacc = Aacc * Ap;
        }
    }
    if (lane == 63) { wA[wave] = Aacc; wB[wave] = Bacc; }
    float eA = __shfl_up(Aacc, 1, 64);
    float eB = __shfl_up(Bacc, 1, 64);
    if (lane == 0) { eA = 1.f; eB = 0.f; }
    __syncthreads();
    float pB = 0.f;
#pragma unroll
    for (int w = 0; w < 3; ++w)
        if (w < wave) pB = wA[w] * pB + wB[w];
    float h = eA * pB + eB;
#pragma unroll
    for (int i = 0; i < 8; ++i) {
        h = a[i] * h + bb[i];
        sd[base + i] = h;
    }
    __syncthreads();
#pragma unroll
    for (int m = 0; m < 2; ++m) {
        int idx = (m * 256 + t) * 4;
        *(float4*)(hsn + (size_t)n * 4096 + b * 2048 + idx) = *(const float4*)(sd + idx);
    }
}

// ---------- ymid = (hs·C_mat[d,:] + D_vec*xsc) * silu(gate), bf16 out ----------
// grid (4, 256): block owns d-range [bx*512, +512), rows [by*16, +16). 1024 blocks.
__global__ __launch_bounds__(256) void ymid_kernel(const float* __restrict__ hsn,
                                                   const float* __restrict__ C_mat,
                                                   const float* __restrict__ D_vec,
                                                   const u16* __restrict__ xsc,
                                                   const u16* __restrict__ xg,
                                                   u16* __restrict__ ymid) {
    const int t = threadIdx.x;
    const int d0 = blockIdx.x * 512 + t * 2;
    const int r0 = blockIdx.y * 16;
    __shared__ float hsv[16 * 16];
    {
        int rl = t >> 4, nn = t & 15;          // t covers all 256 entries
        hsv[t] = hsn[(size_t)nn * 4096 + r0 + rl];
    }
    float c0[16], c1[16];
#pragma unroll
    for (int k = 0; k < 4; ++k) {
        float4 v0 = *(const float4*)(C_mat + (size_t)d0 * 16 + k * 4);
        float4 v1 = *(const float4*)(C_mat + (size_t)(d0 + 1) * 16 + k * 4);
        c0[k * 4 + 0] = v0.x; c0[k * 4 + 1] = v0.y; c0[k * 4 + 2] = v0.z; c0[k * 4 + 3] = v0.w;
        c1[k * 4 + 0] = v1.x; c1[k * 4 + 1] = v1.y; c1[k * 4 + 2] = v1.z; c1[k * 4 + 3] = v1.w;
    }
    const float dv0 = D_vec[d0], dv1 = D_vec[d0 + 1];
    __syncthreads();
#pragma unroll 4
    for (int rl = 0; rl < 16; ++rl) {
        const int r = r0 + rl;
        float h0 = 0.f, h1 = 0.f;
#pragma unroll
        for (int nn = 0; nn < 16; ++nn) {
            float hv = hsv[rl * 16 + nn];      // same addr across lanes: broadcast
            h0 += hv * c0[nn];
            h1 += hv * c1[nn];
        }
        unsigned int xv = *(const unsigned int*)(xsc + (size_t)r * 2048 + d0);
        unsigned int gv = *(const unsigned int*)(xg + (size_t)r * 4096 + 2048 + d0);
        float x0 = u2f((u16)(xv & 0xffffu)), x1 = u2f((u16)(xv >> 16));
        float g0 = u2f((u16)(gv & 0xffffu)), g1 = u2f((u16)(gv >> 16));
        float y0 = (h0 + dv0 * x0) * (g0 / (1.f + expf(-g0)));
        float y1 = (h1 + dv1 * x1) * (g1 / (1.f + expf(-g1)));
        unsigned int o = (unsigned int)f2u(y0) | ((unsigned int)f2u(y1) << 16);
        *(unsigned int*)(ymid + (size_t)r * 2048 + d0) = o;
    }
}

extern "C" void kernel_launch(void* const* d_in, const int* in_sizes, int n_in,
                              void* d_out, int out_size, void* d_ws, size_t ws_size,
                              hipStream_t stream) {
    (void)in_sizes; (void)n_in;
    const float* x      = (const float*)d_in[0];
    const float* ln_g   = (const float*)d_in[1];
    const float* ln_b   = (const float*)d_in[2];
    const float* W_in   = (const float*)d_in[3];
    const float* conv_w = (const float*)d_in[4];
    const float* conv_b = (const float*)d_in[5];
    const float* A_log  = (const float*)d_in[6];
    const float* B_mat  = (const float*)d_in[7];
    const float* C_mat  = (const float*)d_in[8];
    const float* D_vec  = (const float*)d_in[9];
    const float* Wd     = (const float*)d_in[10];
    const float* bd     = (const float*)d_in[11];
    const float* W_out  = (const float*)d_in[12];
    float* out = (float*)d_out;

    // ---- workspace layout (time-overlaid) ----
    char* base = (char*)d_ws;
    u16* Wt_in  = (u16*)base;                          // 4096x1024 bf16 (bufA lo)
    u16* h_ln   = (u16*)base + 4096ull * 1024;         // 4096x1024 bf16 (bufA hi)
    u16* ymid   = (u16*)base;                          // 4096x2048 bf16 (reuse bufA post-GEMM1)
    u16* Wt_ext = (u16*)(base + (16ull << 20));        // 2112x2048 bf16 (Wd^T + B_mat + pad)
    u16* Wt_out = (u16*)(base + (25ull << 20));        // 1024x2048 bf16 (4 MiB)
    u16* xg     = (u16*)(base + (29ull << 20));        // 4096x4096 bf16 (32 MiB)
    u16* xsc    = (u16*)(base + (61ull << 20));        // 4096x2048 bf16 (16 MiB)
    float* delta_acc = (float*)(base + (77ull << 20)); // 4096 f32
    float* Bdotn = delta_acc + 4096;                   // [16][4096] f32
    float* hsn   = Bdotn + 16 * 4096;                  // [16][4096] f32
    u16* planes  = (u16*)(base + (78ull << 20));       // delta: 2 x [4096][2048] bf16 = 32 MiB
    u16* fplanes = (u16*)(base + (78ull << 20));       // fin:   4 x [4096][1024] bf16 = 32 MiB (delta planes dead)
    size_t needed = (77ull << 20) + 4096ull * 4 * (1 + 2 * 16);
    size_t needed_sk = (78ull << 20) + 2ull * 4096 * 2176 * 2;   // 112 MiB (covers 32 MiB planes)

    if (needed > ws_size) {
        hipMemsetAsync(d_out, 0x7F, (size_t)out_size * 4, stream);  // finite sentinel
        return;
    }
    const bool use_sk = (ws_size >= needed_sk);

    // 1. prep: transposes (vectorized stores) + B_mat pad + layernorm + out=x
    prep_kernel<<<14848, 256, 0, stream>>>(W_in, Wt_in, Wd, Wt_ext, W_out, Wt_out,
                                           B_mat, x, ln_g, ln_b, h_ln, out);
    // 2. xg = h @ W_in : 256x256 8-phase kernel (T2-swizzled), 256 blocks, 512 threads
    gemm_xg256<<<256, 512, 0, stream>>>(h_ln, Wt_in, xg, 4096, 4096, 1024);
    // 3. conv + silu (+delta_acc zero for fallback), 4 rows/block, 1024 blocks
    conv_silu_kernel<<<1024, 256, 0, stream>>>(xg, conv_w, conv_b, xsc, delta_acc);
    // 4. delta GEMM
    if (use_sk) {
        // main 2048 cols: 256x256 8-phase split-K=2 -> bf16 planes; (128,2) = 256 blocks
        gemm_delta256<<<dim3(128, 2), 512, 0, stream>>>(xsc, Wt_ext, planes,
                                                        4096, 2048, 2048, 1024);
        // Bdot 16 cols: dedicated MFMA kernel, f32 direct, full K
        bdot_kernel<<<64, 256, 0, stream>>>(xsc, Wt_ext + (size_t)2048 * 2048, Bdotn);
        // combine + bias + softplus rowsum -> delta_acc
        delta_reduce<<<4096, 256, 0, stream>>>(planes, bd, delta_acc);
    } else {
        gemm_delta<<<1056, 256, 0, stream>>>(xsc, Wt_ext, delta_acc, bd, Bdotn,
                                             4096, 2112, 2048);
    }
    // 5. selective scan: 32 chains x 256 threads
    scan_kernel<<<32, 256, 0, stream>>>(delta_acc, Bdotn, A_log, hsn);
    // 6. ymid (into bufA; h_ln/Wt_in dead): C-in-registers, 16 rows/block, 1024 blocks
    ymid_kernel<<<dim3(4, 256), 256, 0, stream>>>(hsn, C_mat, D_vec, xsc, xg, ymid);
    // 7. out += ymid @ W_out
    if (use_sk) {
        // 256x256 8-phase split-K=4 into bf16 planes: (64,4) = 256 blocks (1/CU)
        gemm_fin256<<<dim3(64, 4), 512, 0, stream>>>(ymid, Wt_out, fplanes,
                                                     4096, 1024, 2048, 512);
        fin_reduce<<<2048, 256, 0, stream>>>(fplanes, out);
    } else {
        gemm_fin<<<dim3(256, 2), 256, 0, stream>>>(ymid, Wt_out, out, 4096, 1024, 2048, 1024);
    }
}

// Round 12
// 307.551 us; speedup vs baseline: 1.0240x; 1.0152x over previous
//
#include <hip/hip_runtime.h>
#include <cstdint>
#include <cstddef>

typedef unsigned short u16;
typedef __attribute__((ext_vector_type(4))) float floatx4;
typedef __attribute__((ext_vector_type(8))) __bf16 bf16x8;

// ---------- bf16 helpers ----------
__device__ __forceinline__ float u2f(u16 u) {
    union { unsigned int i; float f; } x;
    x.i = ((unsigned int)u) << 16;
    return x.f;
}
__device__ __forceinline__ u16 f2u(float f) {
    union { float f; unsigned int i; } x;
    x.f = f;
    unsigned int r = x.i + 0x7fffu + ((x.i >> 16) & 1u);   // RNE
    return (u16)(r >> 16);
}

// ---------- XCD-aware swizzle: bid -> (x,y); XCD k owns y-strip [4k,4k+4), x-major ----------
__device__ __forceinline__ void swz(int bid, int& x, int& y) {
    int xcd = bid & 7;
    int lid = bid >> 3;
    x = lid >> 2;
    y = xcd * 4 + (lid & 3);
}

// ---------- prep: 3 weight transposes + B_mat cast-copy/pad + layernorm(+out=x) ----------
__device__ __forceinline__ void tr_tile(const float* __restrict__ in, u16* __restrict__ out,
                                        int K, int N, int bx, int by, float* tile /*32x33*/) {
    int n0 = bx * 32, k0 = by * 32;
    int t = threadIdx.x;
    int r = t >> 3, c4 = (t & 7) * 4;          // input row k0+r, cols n0+c4..+3
    float4 v = *(const float4*)(in + (size_t)(k0 + r) * N + n0 + c4);
    tile[r * 33 + c4 + 0] = v.x;
    tile[r * 33 + c4 + 1] = v.y;
    tile[r * 33 + c4 + 2] = v.z;
    tile[r * 33 + c4 + 3] = v.w;
    __syncthreads();
    int n = t >> 3, kg = (t & 7) * 4;          // output row n0+n, k cols k0+kg..+3
    ushort4 o;
    o.x = f2u(tile[(kg + 0) * 33 + n]);
    o.y = f2u(tile[(kg + 1) * 33 + n]);
    o.z = f2u(tile[(kg + 2) * 33 + n]);
    o.w = f2u(tile[(kg + 3) * 33 + n]);
    *(ushort4*)(out + (size_t)(n0 + n) * K + k0 + kg) = o;
}

// blocks: [0,4096) W_in tr; [4096,8192) Wd tr (rows 0..2047 of Wt_ext);
//         [8192,10240) W_out tr; [10240,14336) layernorm; [14336,14848) B_mat copy+pad (64 rows)
__global__ __launch_bounds__(256)
void prep_kernel(const float* __restrict__ W_in, u16* __restrict__ Wt_in,
                 const float* __restrict__ Wd, u16* __restrict__ Wt_ext,
                 const float* __restrict__ W_out, u16* __restrict__ Wt_out,
                 const float* __restrict__ B_mat,
                 const float* __restrict__ x, const float* __restrict__ gamma,
                 const float* __restrict__ beta, u16* __restrict__ h,
                 float* __restrict__ out) {
    __shared__ float tile[32 * 33];
    int blk = blockIdx.x, t = threadIdx.x;
    if (blk < 4096) {
        tr_tile(W_in, Wt_in, 1024, 4096, blk & 127, blk >> 7, tile);
    } else if (blk < 8192) {
        int b2 = blk - 4096;
        tr_tile(Wd, Wt_ext, 2048, 2048, b2 & 63, b2 >> 6, tile);
    } else if (blk < 10240) {
        int b3 = blk - 8192;
        tr_tile(W_out, Wt_out, 2048, 1024, b3 & 31, b3 >> 5, tile);
    } else if (blk < 14336) {
        int r = blk - 10240;
        const float4* xr = (const float4*)(x + (size_t)r * 1024);
        float4 xv = xr[t];
        ((float4*)(out + (size_t)r * 1024))[t] = xv;   // residual base (fin path adds)
        float s = xv.x + xv.y + xv.z + xv.w;
        float ss = xv.x * xv.x + xv.y * xv.y + xv.z * xv.z + xv.w * xv.w;
#pragma unroll
        for (int off = 32; off > 0; off >>= 1) {
            s += __shfl_down(s, off, 64);
            ss += __shfl_down(ss, off, 64);
        }
        __shared__ float rs[4], rss[4], mu_s, ri_s;
        int wave = t >> 6, lane = t & 63;
        if (lane == 0) { rs[wave] = s; rss[wave] = ss; }
        __syncthreads();
        if (t == 0) {
            float S = rs[0] + rs[1] + rs[2] + rs[3];
            float SS = rss[0] + rss[1] + rss[2] + rss[3];
            float mu = S * (1.f / 1024.f);
            float var = SS * (1.f / 1024.f) - mu * mu;
            mu_s = mu;
            ri_s = rsqrtf(fmaxf(var, 0.f) + 1e-5f);
        }
        __syncthreads();
        float mu = mu_s, ri = ri_s;
        float4 gv = ((const float4*)gamma)[t];
        float4 bv = ((const float4*)beta)[t];
        ushort4 o;
        o.x = f2u((xv.x - mu) * ri * gv.x + bv.x);
        o.y = f2u((xv.y - mu) * ri * gv.y + bv.y);
        o.z = f2u((xv.z - mu) * ri * gv.z + bv.z);
        o.w = f2u((xv.w - mu) * ri * gv.w + bv.w);
        ((ushort4*)(h + (size_t)r * 1024))[t] = o;
    } else {
        // Wt_ext rows 2048..2111: first 16 = B_mat (bf16 cast), rest zero pad
        int idx = (blk - 14336) * 256 + t;         // 0..131071
        int row = 2048 + (idx >> 11), col = idx & 2047;
        u16 v = (row < 2064) ? f2u(B_mat[(size_t)(row - 2048) * 2048 + col]) : (u16)0;
        Wt_ext[(size_t)row * 2048 + col] = v;
    }
}

__device__ __forceinline__ void gl_lds16(const u16* g, u16* l) {
    __builtin_amdgcn_global_load_lds(
        (const __attribute__((address_space(1))) void*)g,
        (__attribute__((address_space(3))) void*)l, 16, 0, 0);
}

// ================== 256x256 8-phase GEMM body (T2 col16-swizzled LDS) ==============
// 512 threads = 8 waves (wr=wid>>2 in {0,1}, wc=wid&3 in {0..3}); per-wave out 128x64.
// LDS 128 KB: As/Bs[2 bufs][2 kk-pages][256 rows][32 cols] bf16.
// T2 swizzle: LDS(row,c16) holds global(row, c16 ^ s(row)), s(row)=(row>>2)&3.
template <int CB, int NB>
__device__ __forceinline__
void ktile256(u16 (&As)[2][16384], u16 (&Bs)[2][16384],
              const u16* __restrict__ gA, const u16* __restrict__ gB,
              int kt, bool doStage, int K,
              int w, int wr, int wc, int l16, int qsw,
              floatx4 (&acc)[8][4]) {
    asm volatile("s_waitcnt vmcnt(0)" ::: "memory");
    __builtin_amdgcn_s_barrier();
    asm volatile("" ::: "memory");
    bf16x8 af[4][2], bfr[4][2];
    const int aBase = wr * 128, bBase = wc * 64;
    // ---- phase 0: read af(mi 0-3) + bfr(ni 0-1); stage A(kt+1) ----
#pragma unroll
    for (int i = 0; i < 4; ++i)
#pragma unroll
        for (int h = 0; h < 2; ++h)
            af[i][h] = *(const bf16x8*)&As[CB][h * 8192 + (aBase + i * 16 + l16) * 32 + qsw * 8];
#pragma unroll
    for (int j = 0; j < 2; ++j)
#pragma unroll
        for (int h = 0; h < 2; ++h)
            bfr[j][h] = *(const bf16x8*)&Bs[CB][h * 8192 + (bBase + j * 16 + l16) * 32 + qsw * 8];
    if (doStage) {
        const u16* p = gA + (size_t)(kt + 1) * 64;
#pragma unroll
        for (int h = 0; h < 2; ++h) {
            gl_lds16(p + h * 32,                  &As[NB][h * 8192 + w * 1024]);
            gl_lds16(p + (size_t)16 * K + h * 32, &As[NB][h * 8192 + w * 1024 + 512]);
        }
    }
    __builtin_amdgcn_s_barrier();
    __builtin_amdgcn_s_setprio(1);
#pragma unroll
    for (int i = 0; i < 4; ++i)
#pragma unroll
        for (int j = 0; j < 2; ++j)
#pragma unroll
            for (int h = 0; h < 2; ++h)
                acc[i][j] = __builtin_amdgcn_mfma_f32_16x16x32_bf16(af[i][h], bfr[j][h], acc[i][j], 0, 0, 0);
    __builtin_amdgcn_s_setprio(0);
    __builtin_amdgcn_s_barrier();
    // ---- phase 1: read bfr(ni 2-3); stage B(kt+1) ----
#pragma unroll
    for (int j = 2; j < 4; ++j)
#pragma unroll
        for (int h = 0; h < 2; ++h)
            bfr[j][h] = *(const bf16x8*)&Bs[CB][h * 8192 + (bBase + j * 16 + l16) * 32 + qsw * 8];
    if (doStage) {
        const u16* p = gB + (size_t)(kt + 1) * 64;
#pragma unroll
        for (int h = 0; h < 2; ++h) {
            gl_lds16(p + h * 32,                  &Bs[NB][h * 8192 + w * 1024]);
            gl_lds16(p + (size_t)16 * K + h * 32, &Bs[NB][h * 8192 + w * 1024 + 512]);
        }
    }
    __builtin_amdgcn_s_barrier();
    __builtin_amdgcn_s_setprio(1);
#pragma unroll
    for (int i = 0; i < 4; ++i)
#pragma unroll
        for (int j = 2; j < 4; ++j)
#pragma unroll
            for (int h = 0; h < 2; ++h)
                acc[i][j] = __builtin_amdgcn_mfma_f32_16x16x32_bf16(af[i][h], bfr[j][h], acc[i][j], 0, 0, 0);
    __builtin_amdgcn_s_setprio(0);
    __builtin_amdgcn_s_barrier();
    // ---- phase 2: read af(mi 4-7); mfma mi4-7 x ni0-1 ----
#pragma unroll
    for (int i = 0; i < 4; ++i)
#pragma unroll
        for (int h = 0; h < 2; ++h)
            af[i][h] = *(const bf16x8*)&As[CB][h * 8192 + (aBase + (4 + i) * 16 + l16) * 32 + qsw * 8];
    __builtin_amdgcn_s_barrier();
    __builtin_amdgcn_s_setprio(1);
#pragma unroll
    for (int i = 0; i < 4; ++i)
#pragma unroll
        for (int j = 0; j < 2; ++j)
#pragma unroll
            for (int h = 0; h < 2; ++h)
                acc[4 + i][j] = __builtin_amdgcn_mfma_f32_16x16x32_bf16(af[i][h], bfr[j][h], acc[4 + i][j], 0, 0, 0);
    __builtin_amdgcn_s_setprio(0);
    __builtin_amdgcn_s_barrier();
    // ---- phase 3: mfma mi4-7 x ni2-3 (no reads) ----
    __builtin_amdgcn_s_setprio(1);
#pragma unroll
    for (int i = 0; i < 4; ++i)
#pragma unroll
        for (int j = 2; j < 4; ++j)
#pragma unroll
            for (int h = 0; h < 2; ++h)
                acc[4 + i][j] = __builtin_amdgcn_mfma_f32_16x16x32_bf16(af[i][h], bfr[j][h], acc[4 + i][j], 0, 0, 0);
    __builtin_amdgcn_s_setprio(0);
    __builtin_amdgcn_s_barrier();
}

// shared 256x256 body; koff/Ksub for split-K; out = bf16 plane of stride N
__device__ __forceinline__
void gemm256_body(const u16* __restrict__ A, const u16* __restrict__ Bt,
                  u16* __restrict__ out, int M, int N, int K,
                  int koff, int Ksub, int bx, int by) {
    __shared__ u16 As[2][16384];   // 64 KB
    __shared__ u16 Bs[2][16384];   // 64 KB
    const int tid = threadIdx.x;
    const int w = tid >> 6, lane = tid & 63;
    const int wr = w >> 2, wc = w & 3;
    const int row0 = by * 256, col0 = bx * 256;
    const int l16 = lane & 15, q = lane >> 4;
    const int sRow = lane >> 2;
    const int sKsw = ((lane & 3) ^ ((lane >> 4) & 3)) * 8;   // T2 source swizzle
    const int qsw = q ^ ((l16 >> 2) & 3);                    // T2 read swizzle

    floatx4 acc[8][4];
#pragma unroll
    for (int i = 0; i < 8; ++i)
#pragma unroll
        for (int j = 0; j < 4; ++j) acc[i][j] = (floatx4){0.f, 0.f, 0.f, 0.f};

    const u16* gA = A + (size_t)(row0 + w * 32 + sRow) * K + koff + sKsw;
    const u16* gB = Bt + (size_t)(col0 + w * 32 + sRow) * K + koff + sKsw;

    // prologue: stage K-tile 0 into buf0 (8 loads/thread)
#pragma unroll
    for (int h = 0; h < 2; ++h) {
        gl_lds16(gA + h * 32,                  &As[0][h * 8192 + w * 1024]);
        gl_lds16(gA + (size_t)16 * K + h * 32, &As[0][h * 8192 + w * 1024 + 512]);
        gl_lds16(gB + h * 32,                  &Bs[0][h * 8192 + w * 1024]);
        gl_lds16(gB + (size_t)16 * K + h * 32, &Bs[0][h * 8192 + w * 1024 + 512]);
    }

    const int nkt = Ksub >> 6;   // must be even
    for (int t2 = 0; t2 < nkt; t2 += 2) {
        ktile256<0, 1>(As, Bs, gA, gB, t2, true, K, w, wr, wc, l16, qsw, acc);
        ktile256<1, 0>(As, Bs, gA, gB, t2 + 1, (t2 + 2) < nkt, K, w, wr, wc, l16, qsw, acc);
    }

    const int mB = row0 + wr * 128;
    const int nB = col0 + wc * 64 + l16;
#pragma unroll
    for (int mi = 0; mi < 8; ++mi)
#pragma unroll
        for (int ni = 0; ni < 4; ++ni)
#pragma unroll
            for (int rr = 0; rr < 4; ++rr)
                out[(size_t)(mB + mi * 16 + q * 4 + rr) * N + nB + ni * 16] =
                    f2u(acc[mi][ni][rr]);
}

// xg = h_ln @ Wt_in : M=N=4096, K=1024; grid 256 = 16x16 tiles, 1 block/CU.
__global__ __launch_bounds__(512, 2)
void gemm_xg256(const u16* __restrict__ A, const u16* __restrict__ Bt,
                u16* __restrict__ out, int M, int N, int K) {
    const int bid = blockIdx.x;
    const int xcd = bid & 7, lid = bid >> 3;       // per-XCD 2-row y-strips
    const int by = xcd * 2 + (lid & 1), bx = lid >> 1;
    gemm256_body(A, Bt, out, M, N, K, 0, K, bx, by);
}

// fin split-K=4 into bf16 planes via 256x256 8-phase body: grid (64,4) = 256 blocks (1/CU)
__global__ __launch_bounds__(512, 2)
void gemm_fin256(const u16* __restrict__ A, const u16* __restrict__ Bt,
                 u16* __restrict__ planes, int M, int N, int K, int Ksub) {
    u16* plane = planes + (size_t)blockIdx.y * M * N;
    const int bid = blockIdx.x;                    // 0..63
    const int bx = bid >> 4, by = bid & 15;        // 4 N-tiles x 16 M-tiles
    gemm256_body(A, Bt, plane, M, N, K, blockIdx.y * Ksub, Ksub, bx, by);
}

// delta main (cols 0..2047) split-K=2 into bf16 planes [2][4096][2048]:
// grid (128,2) = 256 blocks (1/CU). Bdot cols handled by bdot_kernel.
__global__ __launch_bounds__(512, 2)
void gemm_delta256(const u16* __restrict__ A, const u16* __restrict__ Bt,
                   u16* __restrict__ planes, int M, int N, int K, int Ksub) {
    u16* plane = planes + (size_t)blockIdx.y * M * N;   // N = 2048
    const int bid = blockIdx.x;                    // 0..127
    const int xcd = bid & 7, lid = bid >> 3;       // lid 0..15
    const int by = xcd * 2 + (lid & 1), bx = lid >> 1;   // by 0..15, bx 0..7
    gemm256_body(A, Bt, plane, M, N, K, blockIdx.y * Ksub, Ksub, bx, by);
}

// Bdotn[n][r] += sum_{k in chunk} xsc[r,k]*B[n,k]; split-K=8 (grid (64,8)) for
// latency hiding — the per-lane row-scatter loads are intrinsic to the MFMA
// A-fragment layout (row=l16), so we buy parallelism instead of coalescing:
// 512 blocks = 2/CU, 8 waves/CU. Bdotn zeroed by conv_silu_kernel.
__global__ __launch_bounds__(256)
void bdot_kernel(const u16* __restrict__ xsc, const u16* __restrict__ B16,
                 float* __restrict__ Bdotn) {
    const int w = threadIdx.x >> 6, lane = threadIdx.x & 63;
    const int r0 = blockIdx.x * 64 + w * 16;       // 64 rows/block, 16/wave
    const int k0 = blockIdx.y * 256;               // K-chunk
    const int l16 = lane & 15, q = lane >> 4;
    floatx4 acc = (floatx4){0.f, 0.f, 0.f, 0.f};
    const u16* pA = xsc + (size_t)(r0 + l16) * 2048 + k0 + q * 8;
    const u16* pB = B16 + (size_t)l16 * 2048 + k0 + q * 8;
#pragma unroll
    for (int kt = 0; kt < 256; kt += 32) {
        bf16x8 a = *(const bf16x8*)(pA + kt);
        bf16x8 b = *(const bf16x8*)(pB + kt);
        acc = __builtin_amdgcn_mfma_f32_16x16x32_bf16(a, b, acc, 0, 0, 0);
    }
#pragma unroll
    for (int rr = 0; rr < 4; ++rr)
        atomicAdd(&Bdotn[(size_t)l16 * 4096 + r0 + q * 4 + rr], acc[rr]);
}

// ---------- 128x128 tile GEMM, BK=64, 4 waves x (4x4 frags), 32 KB LDS ----------
// EPI 0: bf16 store;  EPI 4: atomicAdd f32 (fallback fin)
template <int EPI>
__device__ __forceinline__
void gemm128_body(const u16* __restrict__ A, const u16* __restrict__ Bt,
                  void* __restrict__ out, int M, int N, int K, int Ksub) {
    __shared__ u16 As[128 * 64];
    __shared__ u16 Bs[128 * 64];
    int bx, by;
    swz(blockIdx.x, bx, by);
    const int tid = threadIdx.x;
    const int wave = tid >> 6, lane = tid & 63;
    const int row0 = by * 128, col0 = bx * 128;
    const int koff = blockIdx.y * Ksub;
    const int l16 = lane & 15, q = lane >> 4;
    const int sRow = lane >> 2, sK = (lane & 3) * 8;

    floatx4 acc[4][4];
#pragma unroll
    for (int i = 0; i < 4; ++i)
#pragma unroll
        for (int j = 0; j < 4; ++j) acc[i][j] = (floatx4){0.f, 0.f, 0.f, 0.f};

    const u16* gA = A + (size_t)(row0 + wave * 32 + sRow) * K + koff + sK;
    const u16* gB = Bt + (size_t)(col0 + wave * 32 + sRow) * K + koff + sK;
    u16* lA = As + wave * 1024;
    u16* lB = Bs + wave * 1024;
    const int rowb = (wave >> 1) * 64, colb = (wave & 1) * 64;

    for (int k0 = 0; k0 < Ksub; k0 += 64) {
#pragma unroll
        for (int h = 0; h < 2; ++h) {
            gl_lds16(gA + h * 32, lA + h * 4096);
            gl_lds16(gA + (size_t)16 * K + h * 32, lA + h * 4096 + 512);
            gl_lds16(gB + h * 32, lB + h * 4096);
            gl_lds16(gB + (size_t)16 * K + h * 32, lB + h * 4096 + 512);
        }
        gA += 64; gB += 64;
        __syncthreads();
#pragma unroll
        for (int h = 0; h < 2; ++h) {
            bf16x8 af[4], bfr[4];
#pragma unroll
            for (int mi = 0; mi < 4; ++mi)
                af[mi] = *(const bf16x8*)(As + h * 4096 + (rowb + mi * 16 + l16) * 32 + q * 8);
#pragma unroll
            for (int ni = 0; ni < 4; ++ni)
                bfr[ni] = *(const bf16x8*)(Bs + h * 4096 + (colb + ni * 16 + l16) * 32 + q * 8);
#pragma unroll
            for (int mi = 0; mi < 4; ++mi)
#pragma unroll
                for (int ni = 0; ni < 4; ++ni)
                    acc[mi][ni] = __builtin_amdgcn_mfma_f32_16x16x32_bf16(
                        af[mi], bfr[ni], acc[mi][ni], 0, 0, 0);
        }
        __syncthreads();
    }

    const int mB = row0 + rowb;
    const int nB = col0 + colb + l16;
    if constexpr (EPI == 0) {
        u16* o = (u16*)out;
#pragma unroll
        for (int mi = 0; mi < 4; ++mi)
#pragma unroll
            for (int ni = 0; ni < 4; ++ni)
#pragma unroll
                for (int rr = 0; rr < 4; ++rr)
                    o[(size_t)(mB + mi * 16 + q * 4 + rr) * N + nB + ni * 16] =
                        f2u(acc[mi][ni][rr]);
    } else {
        float* C = (float*)out;
#pragma unroll
        for (int mi = 0; mi < 4; ++mi)
#pragma unroll
            for (int ni = 0; ni < 4; ++ni)
#pragma unroll
                for (int rr = 0; rr < 4; ++rr)
                    atomicAdd(&C[(size_t)(mB + mi * 16 + q * 4 + rr) * N + nB + ni * 16],
                              acc[mi][ni][rr]);
    }
}

__global__ __launch_bounds__(256)
void gemm_fin(const u16* __restrict__ A, const u16* __restrict__ Bt,
              void* __restrict__ out, int M, int N, int K, int Ksub) {
    gemm128_body<4>(A, Bt, out, M, N, K, Ksub);
}

// out(=residual x) += sum of 4 bf16 planes; 8 elems/thread
__global__ __launch_bounds__(256)
void fin_reduce(const u16* __restrict__ planes, float* __restrict__ out) {
    const size_t PL = (size_t)4096 * 1024;
    const size_t idx = ((size_t)blockIdx.x * 256 + threadIdx.x) * 8;
    float acc[8] = {0.f, 0.f, 0.f, 0.f, 0.f, 0.f, 0.f, 0.f};
#pragma unroll
    for (int p = 0; p < 4; ++p) {
        ushort4 v0 = *(const ushort4*)(planes + p * PL + idx);
        ushort4 v1 = *(const ushort4*)(planes + p * PL + idx + 4);
        acc[0] += u2f(v0.x); acc[1] += u2f(v0.y); acc[2] += u2f(v0.z); acc[3] += u2f(v0.w);
        acc[4] += u2f(v1.x); acc[5] += u2f(v1.y); acc[6] += u2f(v1.z); acc[7] += u2f(v1.w);
    }
    float4 o0 = *(const float4*)(out + idx);
    float4 o1 = *(const float4*)(out + idx + 4);
    o0.x += acc[0]; o0.y += acc[1]; o0.z += acc[2]; o0.w += acc[3];
    o1.x += acc[4]; o1.y += acc[5]; o1.z += acc[6]; o1.w += acc[7];
    *(float4*)(out + idx) = o0;
    *(float4*)(out + idx + 4) = o1;
}

// ---------- delta reduce: row r -> softplus(p0+p1+bd) rowsum (planes stride 2048) ----------
__global__ __launch_bounds__(256)
void delta_reduce(const u16* __restrict__ planes, const float* __restrict__ bias,
                  float* __restrict__ dacc) {
    const int r = blockIdx.x;            // 0..4095
    const int t = threadIdx.x;           // 0..255  (cols t*8..t*8+7 < 2048)
    const size_t PL = (size_t)4096 * 2048;
    const u16* p0 = planes + (size_t)r * 2048 + t * 8;
    const u16* p1 = p0 + PL;
    ushort4 a0 = *(const ushort4*)p0;
    ushort4 a1 = *(const ushort4*)(p0 + 4);
    ushort4 b0 = *(const ushort4*)p1;
    ushort4 b1 = *(const ushort4*)(p1 + 4);
    float4 c0 = *(const float4*)(bias + t * 8);
    float4 c1 = *(const float4*)(bias + t * 8 + 4);
    float e[8];
    e[0] = u2f(a0.x) + u2f(b0.x) + c0.x;
    e[1] = u2f(a0.y) + u2f(b0.y) + c0.y;
    e[2] = u2f(a0.z) + u2f(b0.z) + c0.z;
    e[3] = u2f(a0.w) + u2f(b0.w) + c0.w;
    e[4] = u2f(a1.x) + u2f(b1.x) + c1.x;
    e[5] = u2f(a1.y) + u2f(b1.y) + c1.y;
    e[6] = u2f(a1.z) + u2f(b1.z) + c1.z;
    e[7] = u2f(a1.w) + u2f(b1.w) + c1.w;
    float sv = 0.f;
#pragma unroll
    for (int i = 0; i < 8; ++i)
        sv += (e[i] > 20.f) ? e[i] : log1pf(expf(e[i]));
#pragma unroll
    for (int off = 32; off > 0; off >>= 1)
        sv += __shfl_down(sv, off, 64);
    __shared__ float wsum[4];
    const int wave = t >> 6, lane = t & 63;
    if (lane == 0) wsum[wave] = sv;
    __syncthreads();
    if (t == 0) dacc[r] = wsum[0] + wsum[1] + wsum[2] + wsum[3];
}

// ---------- delta GEMM fallback (ws too small): 128M x 64N tile, BK=128 ----------
__global__ __launch_bounds__(256)
void gemm_delta(const u16* __restrict__ A, const u16* __restrict__ Bt,
                float* __restrict__ dacc, const float* __restrict__ bias,
                float* __restrict__ Bdotn, int M, int N, int K) {
    __shared__ u16 As[128 * 128];
    __shared__ u16 Bs[64 * 128];
    int bx, by;
    swz(blockIdx.x, bx, by);
    const int tid = threadIdx.x;
    const int wave = tid >> 6, lane = tid & 63;
    const int row0 = by * 128, col0 = bx * 64;
    const int l16 = lane & 15, q = lane >> 4;
    const int sRow = lane >> 2, sK = (lane & 3) * 8;

    floatx4 acc[2][4];
#pragma unroll
    for (int i = 0; i < 2; ++i)
#pragma unroll
        for (int j = 0; j < 4; ++j) acc[i][j] = (floatx4){0.f, 0.f, 0.f, 0.f};

    const u16* gA = A + (size_t)(row0 + wave * 32 + sRow) * K + sK;
    const u16* gB = Bt + (size_t)(col0 + wave * 16 + sRow) * K + sK;
    u16* lA = As + wave * 1024;
    u16* lB = Bs + wave * 512;
    const int rowb = wave * 32;

    for (int k0 = 0; k0 < K; k0 += 128) {
#pragma unroll
        for (int h = 0; h < 4; ++h) {
            gl_lds16(gA + h * 32, lA + h * 4096);
            gl_lds16(gA + (size_t)16 * K + h * 32, lA + h * 4096 + 512);
            gl_lds16(gB + h * 32, lB + h * 2048);
        }
        gA += 128; gB += 128;
        __syncthreads();
#pragma unroll
        for (int h = 0; h < 4; ++h) {
            bf16x8 af[2], bfr[4];
#pragma unroll
            for (int mi = 0; mi < 2; ++mi)
                af[mi] = *(const bf16x8*)(As + h * 4096 + (rowb + mi * 16 + l16) * 32 + q * 8);
#pragma unroll
            for (int ni = 0; ni < 4; ++ni)
                bfr[ni] = *(const bf16x8*)(Bs + h * 2048 + (ni * 16 + l16) * 32 + q * 8);
#pragma unroll
            for (int mi = 0; mi < 2; ++mi)
#pragma unroll
                for (int ni = 0; ni < 4; ++ni)
                    acc[mi][ni] = __builtin_amdgcn_mfma_f32_16x16x32_bf16(
                        af[mi], bfr[ni], acc[mi][ni], 0, 0, 0);
        }
        __syncthreads();
    }

    const int mB = row0 + rowb;
    const int nB = col0 + l16;
    if (col0 < 2048) {
#pragma unroll
        for (int mi = 0; mi < 2; ++mi) {
#pragma unroll
            for (int rr = 0; rr < 4; ++rr) {
                float sv = 0.f;
#pragma unroll
                for (int ni = 0; ni < 4; ++ni) {
                    float t2 = acc[mi][ni][rr] + bias[nB + ni * 16];
                    sv += (t2 > 20.f) ? t2 : log1pf(expf(t2));
                }
#pragma unroll
                for (int off = 1; off < 16; off <<= 1)
                    sv += __shfl_xor(sv, off, 64);
                if (l16 == 0)
                    atomicAdd(&dacc[mB + mi * 16 + q * 4 + rr], sv);
            }
        }
    } else {
#pragma unroll
        for (int mi = 0; mi < 2; ++mi)
#pragma unroll
            for (int rr = 0; rr < 4; ++rr)
                Bdotn[(size_t)l16 * 4096 + mB + mi * 16 + q * 4 + rr] =
                    acc[mi][0][rr];
    }
}

// ---------- lean conv(K=4)+SiLU, 4 rows/block (1024 blocks) + delta_acc/Bdotn zero ----------
__global__ __launch_bounds__(256) void conv_silu_kernel(const u16* __restrict__ xg,
                                                        const float* __restrict__ conv_w,
                                                        const float* __restrict__ conv_b,
                                                        u16* __restrict__ xsc,
                                                        float* __restrict__ delta_acc,
                                                        float* __restrict__ Bdotn) {
    int r0 = blockIdx.x * 4;                  // 4 rows/block; 2048 % 4 == 0
    int l0 = r0 & 2047, bb = r0 >> 11;
    int t = threadIdx.x, d8 = t * 8;
    if (t < 4) delta_acc[r0 + t] = 0.f;       // zero before fallback path's atomics
    if (t < 64) Bdotn[(size_t)blockIdx.x * 64 + t] = 0.f;   // 1024*64 = 16*4096 exact

    ushort4 rw[7][2];                         // rows l0-3 .. l0+3
#pragma unroll
    for (int j = 0; j < 7; ++j) {
        int ls = l0 + j - 3;
        if (ls >= 0) {
            const u16* row = xg + (size_t)((bb << 11) + ls) * 4096 + d8;
            rw[j][0] = *(const ushort4*)row;
            rw[j][1] = *(const ushort4*)(row + 4);
        } else {
            rw[j][0] = (ushort4){0, 0, 0, 0};
            rw[j][1] = (ushort4){0, 0, 0, 0};
        }
    }
    float w[8][4];
#pragma unroll
    for (int j = 0; j < 8; ++j) {
        float4 wv = *(const float4*)(conv_w + (size_t)(d8 + j) * 4);
        w[j][0] = wv.x; w[j][1] = wv.y; w[j][2] = wv.z; w[j][3] = wv.w;
    }
    float cb[8];
    {
        float4 b0 = *(const float4*)(conv_b + d8);
        float4 b1 = *(const float4*)(conv_b + d8 + 4);
        cb[0] = b0.x; cb[1] = b0.y; cb[2] = b0.z; cb[3] = b0.w;
        cb[4] = b1.x; cb[5] = b1.y; cb[6] = b1.z; cb[7] = b1.w;
    }
#pragma unroll
    for (int i = 0; i < 4; ++i) {
        float xs[8];
#pragma unroll
        for (int j = 0; j < 8; ++j) xs[j] = cb[j];
#pragma unroll
        for (int k = 0; k < 4; ++k) {
            ushort4 u0 = rw[i + k][0], u1 = rw[i + k][1];
            xs[0] += w[0][k] * u2f(u0.x); xs[1] += w[1][k] * u2f(u0.y);
            xs[2] += w[2][k] * u2f(u0.z); xs[3] += w[3][k] * u2f(u0.w);
            xs[4] += w[4][k] * u2f(u1.x); xs[5] += w[5][k] * u2f(u1.y);
            xs[6] += w[6][k] * u2f(u1.z); xs[7] += w[7][k] * u2f(u1.w);
        }
        ushort4 o0, o1;
        o0.x = f2u(xs[0] / (1.f + expf(-xs[0])));
        o0.y = f2u(xs[1] / (1.f + expf(-xs[1])));
        o0.z = f2u(xs[2] / (1.f + expf(-xs[2])));
        o0.w = f2u(xs[3] / (1.f + expf(-xs[3])));
        o1.x = f2u(xs[4] / (1.f + expf(-xs[4])));
        o1.y = f2u(xs[5] / (1.f + expf(-xs[5])));
        o1.z = f2u(xs[6] / (1.f + expf(-xs[6])));
        o1.w = f2u(xs[7] / (1.f + expf(-xs[7])));
        u16* orow = xsc + (size_t)(r0 + i) * 2048 + d8;
        *(ushort4*)orow = o0;
        *(ushort4*)(orow + 4) = o1;
    }
}

// ---------- selective scan: 32 chains, 256 threads (4 waves) each ----------
__global__ __launch_bounds__(256) void scan_kernel(const float* __restrict__ delta_acc,
                                                   const float* __restrict__ Bdotn,
                                                   const float* __restrict__ A_log,
                                                   float* __restrict__ hsn) {
    int chain = blockIdx.x;                 // 0..31
    int b = chain >> 4, n = chain & 15;
    int t = threadIdx.x;                    // 0..255
    int wave = t >> 6, lane = t & 63;
    __shared__ float sd[2048], sb[2048];
    __shared__ float wA[4], wB[4];
#pragma unroll
    for (int m = 0; m < 2; ++m) {
        int idx = (m * 256 + t) * 4;
        *(float4*)(sd + idx) = *(const float4*)(delta_acc + b * 2048 + idx);
        *(float4*)(sb + idx) = *(const float4*)(Bdotn + (size_t)n * 4096 + b * 2048 + idx);
    }
    __syncthreads();
    float An = -expf(A_log[n]);
    int base = t * 8;
    float a[8], bb[8];
#pragma unroll
    for (int i = 0; i < 8; ++i) {
        float dl = sd[base + i] * (1.f / 2048.f);
        a[i] = expf(dl * An);
        bb[i] = sb[base + i] * dl;
    }
    float Aacc = 1.f, Bacc = 0.f;
#pragma unroll
    for (int i = 0; i < 8; ++i) {
        Bacc = a[i] * Bacc + bb[i];
        Aacc = a[i] * Aacc;
    }
#pragma unroll
    for (int d = 1; d < 64; d <<= 1) {
        float Ap = __shfl_up(Aacc, d, 64);
        float Bp = __shfl_up(Bacc, d, 64);
        if (lane >= d) {
            Bacc = Aacc * Bp + Bacc;
            Aacc = Aacc * Ap;
        }
    }
    if (lane == 63) { wA[wave] = Aacc; wB[wave] = Bacc; }
    float eA = __shfl_up(Aacc, 1, 64);
    float eB = __shfl_up(Bacc, 1, 64);
    if (lane == 0) { eA = 1.f; eB = 0.f; }
    __syncthreads();
    float pB = 0.f;
#pragma unroll
    for (int w = 0; w < 3; ++w)
        if (w < wave) pB = wA[w] * pB + wB[w];
    float h = eA * pB + eB;
#pragma unroll
    for (int i = 0; i < 8; ++i) {
        h = a[i] * h + bb[i];
        sd[base + i] = h;
    }
    __syncthreads();
#pragma unroll
    for (int m = 0; m < 2; ++m) {
        int idx = (m * 256 + t) * 4;
        *(float4*)(hsn + (size_t)n * 4096 + b * 2048 + idx) = *(const float4*)(sd + idx);
    }
}

// ---------- ymid = (hs·C_mat[d,:] + D_vec*xsc) * silu(gate), bf16 out ----------
// grid (4, 256): block owns d-range [bx*512, +512), rows [by*16, +16). 1024 blocks.
__global__ __launch_bounds__(256) void ymid_kernel(const float* __restrict__ hsn,
                                                   const float* __restrict__ C_mat,
                                                   const float* __restrict__ D_vec,
                                                   const u16* __restrict__ xsc,
                                                   const u16* __restrict__ xg,
                                                   u16* __restrict__ ymid) {
    const int t = threadIdx.x;
    const int d0 = blockIdx.x * 512 + t * 2;
    const int r0 = blockIdx.y * 16;
    __shared__ float hsv[16 * 16];
    {
        int rl = t >> 4, nn = t & 15;          // t covers all 256 entries
        hsv[t] = hsn[(size_t)nn * 4096 + r0 + rl];
    }
    float c0[16], c1[16];
#pragma unroll
    for (int k = 0; k < 4; ++k) {
        float4 v0 = *(const float4*)(C_mat + (size_t)d0 * 16 + k * 4);
        float4 v1 = *(const float4*)(C_mat + (size_t)(d0 + 1) * 16 + k * 4);
        c0[k * 4 + 0] = v0.x; c0[k * 4 + 1] = v0.y; c0[k * 4 + 2] = v0.z; c0[k * 4 + 3] = v0.w;
        c1[k * 4 + 0] = v1.x; c1[k * 4 + 1] = v1.y; c1[k * 4 + 2] = v1.z; c1[k * 4 + 3] = v1.w;
    }
    const float dv0 = D_vec[d0], dv1 = D_vec[d0 + 1];
    __syncthreads();
#pragma unroll 4
    for (int rl = 0; rl < 16; ++rl) {
        const int r = r0 + rl;
        float h0 = 0.f, h1 = 0.f;
#pragma unroll
        for (int nn = 0; nn < 16; ++nn) {
            float hv = hsv[rl * 16 + nn];      // same addr across lanes: broadcast
            h0 += hv * c0[nn];
            h1 += hv * c1[nn];
        }
        unsigned int xv = *(const unsigned int*)(xsc + (size_t)r * 2048 + d0);
        unsigned int gv = *(const unsigned int*)(xg + (size_t)r * 4096 + 2048 + d0);
        float x0 = u2f((u16)(xv & 0xffffu)), x1 = u2f((u16)(xv >> 16));
        float g0 = u2f((u16)(gv & 0xffffu)), g1 = u2f((u16)(gv >> 16));
        float y0 = (h0 + dv0 * x0) * (g0 / (1.f + expf(-g0)));
        float y1 = (h1 + dv1 * x1) * (g1 / (1.f + expf(-g1)));
        unsigned int o = (unsigned int)f2u(y0) | ((unsigned int)f2u(y1) << 16);
        *(unsigned int*)(ymid + (size_t)r * 2048 + d0) = o;
    }
}

extern "C" void kernel_launch(void* const* d_in, const int* in_sizes, int n_in,
                              void* d_out, int out_size, void* d_ws, size_t ws_size,
                              hipStream_t stream) {
    (void)in_sizes; (void)n_in;
    const float* x      = (const float*)d_in[0];
    const float* ln_g   = (const float*)d_in[1];
    const float* ln_b   = (const float*)d_in[2];
    const float* W_in   = (const float*)d_in[3];
    const float* conv_w = (const float*)d_in[4];
    const float* conv_b = (const float*)d_in[5];
    const float* A_log  = (const float*)d_in[6];
    const float* B_mat  = (const float*)d_in[7];
    const float* C_mat  = (const float*)d_in[8];
    const float* D_vec  = (const float*)d_in[9];
    const float* Wd     = (const float*)d_in[10];
    const float* bd     = (const float*)d_in[11];
    const float* W_out  = (const float*)d_in[12];
    float* out = (float*)d_out;

    // ---- workspace layout (time-overlaid) ----
    char* base = (char*)d_ws;
    u16* Wt_in  = (u16*)base;                          // 4096x1024 bf16 (bufA lo)
    u16* h_ln   = (u16*)base + 4096ull * 1024;         // 4096x1024 bf16 (bufA hi)
    u16* ymid   = (u16*)base;                          // 4096x2048 bf16 (reuse bufA post-GEMM1)
    u16* Wt_ext = (u16*)(base + (16ull << 20));        // 2112x2048 bf16 (Wd^T + B_mat + pad)
    u16* Wt_out = (u16*)(base + (25ull << 20));        // 1024x2048 bf16 (4 MiB)
    u16* xg     = (u16*)(base + (29ull << 20));        // 4096x4096 bf16 (32 MiB)
    u16* xsc    = (u16*)(base + (61ull << 20));        // 4096x2048 bf16 (16 MiB)
    float* delta_acc = (float*)(base + (77ull << 20)); // 4096 f32
    float* Bdotn = delta_acc + 4096;                   // [16][4096] f32
    float* hsn   = Bdotn + 16 * 4096;                  // [16][4096] f32
    u16* planes  = (u16*)(base + (78ull << 20));       // delta: 2 x [4096][2048] bf16 = 32 MiB
    u16* fplanes = (u16*)(base + (78ull << 20));       // fin:   4 x [4096][1024] bf16 = 32 MiB (delta planes dead)
    size_t needed = (77ull << 20) + 4096ull * 4 * (1 + 2 * 16);
    size_t needed_sk = (78ull << 20) + 2ull * 4096 * 2176 * 2;   // 112 MiB (covers 32 MiB planes)

    if (needed > ws_size) {
        hipMemsetAsync(d_out, 0x7F, (size_t)out_size * 4, stream);  // finite sentinel
        return;
    }
    const bool use_sk = (ws_size >= needed_sk);

    // 1. prep: transposes (vectorized stores) + B_mat pad + layernorm + out=x
    prep_kernel<<<14848, 256, 0, stream>>>(W_in, Wt_in, Wd, Wt_ext, W_out, Wt_out,
                                           B_mat, x, ln_g, ln_b, h_ln, out);
    // 2. xg = h @ W_in : 256x256 8-phase kernel (T2-swizzled), 256 blocks, 512 threads
    gemm_xg256<<<256, 512, 0, stream>>>(h_ln, Wt_in, xg, 4096, 4096, 1024);
    // 3. conv + silu (+delta_acc/Bdotn zero), 4 rows/block, 1024 blocks
    conv_silu_kernel<<<1024, 256, 0, stream>>>(xg, conv_w, conv_b, xsc, delta_acc, Bdotn);
    // 4. delta GEMM
    if (use_sk) {
        // main 2048 cols: 256x256 8-phase split-K=2 -> bf16 planes; (128,2) = 256 blocks
        gemm_delta256<<<dim3(128, 2), 512, 0, stream>>>(xsc, Wt_ext, planes,
                                                        4096, 2048, 2048, 1024);
        // Bdot 16 cols: split-K=8 MFMA kernel, f32 atomics (Bdotn pre-zeroed by conv)
        bdot_kernel<<<dim3(64, 8), 256, 0, stream>>>(xsc, Wt_ext + (size_t)2048 * 2048, Bdotn);
        // combine + bias + softplus rowsum -> delta_acc
        delta_reduce<<<4096, 256, 0, stream>>>(planes, bd, delta_acc);
    } else {
        gemm_delta<<<1056, 256, 0, stream>>>(xsc, Wt_ext, delta_acc, bd, Bdotn,
                                             4096, 2112, 2048);
    }
    // 5. selective scan: 32 chains x 256 threads
    scan_kernel<<<32, 256, 0, stream>>>(delta_acc, Bdotn, A_log, hsn);
    // 6. ymid (into bufA; h_ln/Wt_in dead): C-in-registers, 16 rows/block, 1024 blocks
    ymid_kernel<<<dim3(4, 256), 256, 0, stream>>>(hsn, C_mat, D_vec, xsc, xg, ymid);
    // 7. out += ymid @ W_out
    if (use_sk) {
        // 256x256 8-phase split-K=4 into bf16 planes: (64,4) = 256 blocks (1/CU)
        gemm_fin256<<<dim3(64, 4), 512, 0, stream>>>(ymid, Wt_out, fplanes,
                                                     4096, 1024, 2048, 512);
        fin_reduce<<<2048, 256, 0, stream>>>(fplanes, out);
    } else {
        gemm_fin<<<dim3(256, 2), 256, 0, stream>>>(ymid, Wt_out, out, 4096, 1024, 2048, 1024);
    }
}

// Round 13
// 296.111 us; speedup vs baseline: 1.0635x; 1.0386x over previous
//
#include <hip/hip_runtime.h>
#include <cstdint>
#include <cstddef>

typedef unsigned short u16;
typedef __attribute__((ext_vector_type(4))) float floatx4;
typedef __attribute__((ext_vector_type(8))) __bf16 bf16x8;

// ---------- bf16 helpers ----------
__device__ __forceinline__ float u2f(u16 u) {
    union { unsigned int i; float f; } x;
    x.i = ((unsigned int)u) << 16;
    return x.f;
}
__device__ __forceinline__ u16 f2u(float f) {
    union { float f; unsigned int i; } x;
    x.f = f;
    unsigned int r = x.i + 0x7fffu + ((x.i >> 16) & 1u);   // RNE
    return (u16)(r >> 16);
}

// ---------- XCD-aware swizzle: bid -> (x,y); XCD k owns y-strip [4k,4k+4), x-major ----------
__device__ __forceinline__ void swz(int bid, int& x, int& y) {
    int xcd = bid & 7;
    int lid = bid >> 3;
    x = lid >> 2;
    y = xcd * 4 + (lid & 3);
}

// ---------- prep: 3 weight transposes + B_mat cast-copy/pad + layernorm(+out=x) ----------
__device__ __forceinline__ void tr_tile(const float* __restrict__ in, u16* __restrict__ out,
                                        int K, int N, int bx, int by, float* tile /*32x33*/) {
    int n0 = bx * 32, k0 = by * 32;
    int t = threadIdx.x;
    int r = t >> 3, c4 = (t & 7) * 4;          // input row k0+r, cols n0+c4..+3
    float4 v = *(const float4*)(in + (size_t)(k0 + r) * N + n0 + c4);
    tile[r * 33 + c4 + 0] = v.x;
    tile[r * 33 + c4 + 1] = v.y;
    tile[r * 33 + c4 + 2] = v.z;
    tile[r * 33 + c4 + 3] = v.w;
    __syncthreads();
    int n = t >> 3, kg = (t & 7) * 4;          // output row n0+n, k cols k0+kg..+3
    ushort4 o;
    o.x = f2u(tile[(kg + 0) * 33 + n]);
    o.y = f2u(tile[(kg + 1) * 33 + n]);
    o.z = f2u(tile[(kg + 2) * 33 + n]);
    o.w = f2u(tile[(kg + 3) * 33 + n]);
    *(ushort4*)(out + (size_t)(n0 + n) * K + k0 + kg) = o;
}

// blocks: [0,4096) W_in tr; [4096,8192) Wd tr (rows 0..2047 of Wt_ext);
//         [8192,10240) W_out tr; [10240,14336) layernorm; [14336,14848) B_mat copy+pad (64 rows)
__global__ __launch_bounds__(256)
void prep_kernel(const float* __restrict__ W_in, u16* __restrict__ Wt_in,
                 const float* __restrict__ Wd, u16* __restrict__ Wt_ext,
                 const float* __restrict__ W_out, u16* __restrict__ Wt_out,
                 const float* __restrict__ B_mat,
                 const float* __restrict__ x, const float* __restrict__ gamma,
                 const float* __restrict__ beta, u16* __restrict__ h,
                 float* __restrict__ out) {
    __shared__ float tile[32 * 33];
    int blk = blockIdx.x, t = threadIdx.x;
    if (blk < 4096) {
        tr_tile(W_in, Wt_in, 1024, 4096, blk & 127, blk >> 7, tile);
    } else if (blk < 8192) {
        int b2 = blk - 4096;
        tr_tile(Wd, Wt_ext, 2048, 2048, b2 & 63, b2 >> 6, tile);
    } else if (blk < 10240) {
        int b3 = blk - 8192;
        tr_tile(W_out, Wt_out, 2048, 1024, b3 & 31, b3 >> 5, tile);
    } else if (blk < 14336) {
        int r = blk - 10240;
        const float4* xr = (const float4*)(x + (size_t)r * 1024);
        float4 xv = xr[t];
        ((float4*)(out + (size_t)r * 1024))[t] = xv;   // residual base (fin path adds)
        float s = xv.x + xv.y + xv.z + xv.w;
        float ss = xv.x * xv.x + xv.y * xv.y + xv.z * xv.z + xv.w * xv.w;
#pragma unroll
        for (int off = 32; off > 0; off >>= 1) {
            s += __shfl_down(s, off, 64);
            ss += __shfl_down(ss, off, 64);
        }
        __shared__ float rs[4], rss[4], mu_s, ri_s;
        int wave = t >> 6, lane = t & 63;
        if (lane == 0) { rs[wave] = s; rss[wave] = ss; }
        __syncthreads();
        if (t == 0) {
            float S = rs[0] + rs[1] + rs[2] + rs[3];
            float SS = rss[0] + rss[1] + rss[2] + rss[3];
            float mu = S * (1.f / 1024.f);
            float var = SS * (1.f / 1024.f) - mu * mu;
            mu_s = mu;
            ri_s = rsqrtf(fmaxf(var, 0.f) + 1e-5f);
        }
        __syncthreads();
        float mu = mu_s, ri = ri_s;
        float4 gv = ((const float4*)gamma)[t];
        float4 bv = ((const float4*)beta)[t];
        ushort4 o;
        o.x = f2u((xv.x - mu) * ri * gv.x + bv.x);
        o.y = f2u((xv.y - mu) * ri * gv.y + bv.y);
        o.z = f2u((xv.z - mu) * ri * gv.z + bv.z);
        o.w = f2u((xv.w - mu) * ri * gv.w + bv.w);
        ((ushort4*)(h + (size_t)r * 1024))[t] = o;
    } else {
        // Wt_ext rows 2048..2111: first 16 = B_mat (bf16 cast), rest zero pad
        int idx = (blk - 14336) * 256 + t;         // 0..131071
        int row = 2048 + (idx >> 11), col = idx & 2047;
        u16 v = (row < 2064) ? f2u(B_mat[(size_t)(row - 2048) * 2048 + col]) : (u16)0;
        Wt_ext[(size_t)row * 2048 + col] = v;
    }
}

__device__ __forceinline__ void gl_lds16(const u16* g, u16* l) {
    __builtin_amdgcn_global_load_lds(
        (const __attribute__((address_space(1))) void*)g,
        (__attribute__((address_space(3))) void*)l, 16, 0, 0);
}

// ================== 256x256 8-phase GEMM body (T2 col16-swizzled LDS) ==============
// 512 threads = 8 waves (wr=wid>>2 in {0,1}, wc=wid&3 in {0..3}); per-wave out 128x64.
// LDS 128 KB: As/Bs[2 bufs][2 kk-pages][256 rows][32 cols] bf16.
// T2 swizzle: LDS(row,c16) holds global(row, c16 ^ s(row)), s(row)=(row>>2)&3.
// Phases 2+3 merged (phase 3 had no memory ops to interleave -> barrier was
// lockstep-only; correctness barriers = tile-top vmcnt+bar and buffer-swap bars).
template <int CB, int NB>
__device__ __forceinline__
void ktile256(u16 (&As)[2][16384], u16 (&Bs)[2][16384],
              const u16* __restrict__ gA, const u16* __restrict__ gB,
              int kt, bool doStage, int K,
              int w, int wr, int wc, int l16, int qsw,
              floatx4 (&acc)[8][4]) {
    asm volatile("s_waitcnt vmcnt(0)" ::: "memory");
    __builtin_amdgcn_s_barrier();
    asm volatile("" ::: "memory");
    bf16x8 af[4][2], bfr[4][2];
    const int aBase = wr * 128, bBase = wc * 64;
    // ---- phase 0: read af(mi 0-3) + bfr(ni 0-1); stage A(kt+1) ----
#pragma unroll
    for (int i = 0; i < 4; ++i)
#pragma unroll
        for (int h = 0; h < 2; ++h)
            af[i][h] = *(const bf16x8*)&As[CB][h * 8192 + (aBase + i * 16 + l16) * 32 + qsw * 8];
#pragma unroll
    for (int j = 0; j < 2; ++j)
#pragma unroll
        for (int h = 0; h < 2; ++h)
            bfr[j][h] = *(const bf16x8*)&Bs[CB][h * 8192 + (bBase + j * 16 + l16) * 32 + qsw * 8];
    if (doStage) {
        const u16* p = gA + (size_t)(kt + 1) * 64;
#pragma unroll
        for (int h = 0; h < 2; ++h) {
            gl_lds16(p + h * 32,                  &As[NB][h * 8192 + w * 1024]);
            gl_lds16(p + (size_t)16 * K + h * 32, &As[NB][h * 8192 + w * 1024 + 512]);
        }
    }
    __builtin_amdgcn_s_barrier();
    __builtin_amdgcn_s_setprio(1);
#pragma unroll
    for (int i = 0; i < 4; ++i)
#pragma unroll
        for (int j = 0; j < 2; ++j)
#pragma unroll
            for (int h = 0; h < 2; ++h)
                acc[i][j] = __builtin_amdgcn_mfma_f32_16x16x32_bf16(af[i][h], bfr[j][h], acc[i][j], 0, 0, 0);
    __builtin_amdgcn_s_setprio(0);
    __builtin_amdgcn_s_barrier();
    // ---- phase 1: read bfr(ni 2-3); stage B(kt+1) ----
#pragma unroll
    for (int j = 2; j < 4; ++j)
#pragma unroll
        for (int h = 0; h < 2; ++h)
            bfr[j][h] = *(const bf16x8*)&Bs[CB][h * 8192 + (bBase + j * 16 + l16) * 32 + qsw * 8];
    if (doStage) {
        const u16* p = gB + (size_t)(kt + 1) * 64;
#pragma unroll
        for (int h = 0; h < 2; ++h) {
            gl_lds16(p + h * 32,                  &Bs[NB][h * 8192 + w * 1024]);
            gl_lds16(p + (size_t)16 * K + h * 32, &Bs[NB][h * 8192 + w * 1024 + 512]);
        }
    }
    __builtin_amdgcn_s_barrier();
    __builtin_amdgcn_s_setprio(1);
#pragma unroll
    for (int i = 0; i < 4; ++i)
#pragma unroll
        for (int j = 2; j < 4; ++j)
#pragma unroll
            for (int h = 0; h < 2; ++h)
                acc[i][j] = __builtin_amdgcn_mfma_f32_16x16x32_bf16(af[i][h], bfr[j][h], acc[i][j], 0, 0, 0);
    __builtin_amdgcn_s_setprio(0);
    __builtin_amdgcn_s_barrier();
    // ---- phase 2+3 merged: read af(mi 4-7); mfma mi4-7 x ni0-3 (32 MFMA cluster) ----
#pragma unroll
    for (int i = 0; i < 4; ++i)
#pragma unroll
        for (int h = 0; h < 2; ++h)
            af[i][h] = *(const bf16x8*)&As[CB][h * 8192 + (aBase + (4 + i) * 16 + l16) * 32 + qsw * 8];
    __builtin_amdgcn_s_barrier();
    __builtin_amdgcn_s_setprio(1);
#pragma unroll
    for (int i = 0; i < 4; ++i)
#pragma unroll
        for (int j = 0; j < 4; ++j)
#pragma unroll
            for (int h = 0; h < 2; ++h)
                acc[4 + i][j] = __builtin_amdgcn_mfma_f32_16x16x32_bf16(af[i][h], bfr[j][h], acc[4 + i][j], 0, 0, 0);
    __builtin_amdgcn_s_setprio(0);
    __builtin_amdgcn_s_barrier();
}

// shared 256x256 body; koff/Ksub for split-K; out = bf16 plane of stride N
__device__ __forceinline__
void gemm256_body(const u16* __restrict__ A, const u16* __restrict__ Bt,
                  u16* __restrict__ out, int M, int N, int K,
                  int koff, int Ksub, int bx, int by) {
    __shared__ u16 As[2][16384];   // 64 KB
    __shared__ u16 Bs[2][16384];   // 64 KB
    const int tid = threadIdx.x;
    const int w = tid >> 6, lane = tid & 63;
    const int wr = w >> 2, wc = w & 3;
    const int row0 = by * 256, col0 = bx * 256;
    const int l16 = lane & 15, q = lane >> 4;
    const int sRow = lane >> 2;
    const int sKsw = ((lane & 3) ^ ((lane >> 4) & 3)) * 8;   // T2 source swizzle
    const int qsw = q ^ ((l16 >> 2) & 3);                    // T2 read swizzle

    floatx4 acc[8][4];
#pragma unroll
    for (int i = 0; i < 8; ++i)
#pragma unroll
        for (int j = 0; j < 4; ++j) acc[i][j] = (floatx4){0.f, 0.f, 0.f, 0.f};

    const u16* gA = A + (size_t)(row0 + w * 32 + sRow) * K + koff + sKsw;
    const u16* gB = Bt + (size_t)(col0 + w * 32 + sRow) * K + koff + sKsw;

    // prologue: stage K-tile 0 into buf0 (8 loads/thread)
#pragma unroll
    for (int h = 0; h < 2; ++h) {
        gl_lds16(gA + h * 32,                  &As[0][h * 8192 + w * 1024]);
        gl_lds16(gA + (size_t)16 * K + h * 32, &As[0][h * 8192 + w * 1024 + 512]);
        gl_lds16(gB + h * 32,                  &Bs[0][h * 8192 + w * 1024]);
        gl_lds16(gB + (size_t)16 * K + h * 32, &Bs[0][h * 8192 + w * 1024 + 512]);
    }

    const int nkt = Ksub >> 6;   // must be even
    for (int t2 = 0; t2 < nkt; t2 += 2) {
        ktile256<0, 1>(As, Bs, gA, gB, t2, true, K, w, wr, wc, l16, qsw, acc);
        ktile256<1, 0>(As, Bs, gA, gB, t2 + 1, (t2 + 2) < nkt, K, w, wr, wc, l16, qsw, acc);
    }

    const int mB = row0 + wr * 128;
    const int nB = col0 + wc * 64 + l16;
#pragma unroll
    for (int mi = 0; mi < 8; ++mi)
#pragma unroll
        for (int ni = 0; ni < 4; ++ni)
#pragma unroll
            for (int rr = 0; rr < 4; ++rr)
                out[(size_t)(mB + mi * 16 + q * 4 + rr) * N + nB + ni * 16] =
                    f2u(acc[mi][ni][rr]);
}

// xg = h_ln @ Wt_in : M=N=4096, K=1024; grid 256 = 16x16 tiles, 1 block/CU.
__global__ __launch_bounds__(512, 2)
void gemm_xg256(const u16* __restrict__ A, const u16* __restrict__ Bt,
                u16* __restrict__ out, int M, int N, int K) {
    const int bid = blockIdx.x;
    const int xcd = bid & 7, lid = bid >> 3;       // per-XCD 2-row y-strips
    const int by = xcd * 2 + (lid & 1), bx = lid >> 1;
    gemm256_body(A, Bt, out, M, N, K, 0, K, bx, by);
}

// fin split-K=4 into bf16 planes via 256x256 8-phase body: grid (64,4) = 256 blocks (1/CU)
__global__ __launch_bounds__(512, 2)
void gemm_fin256(const u16* __restrict__ A, const u16* __restrict__ Bt,
                 u16* __restrict__ planes, int M, int N, int K, int Ksub) {
    u16* plane = planes + (size_t)blockIdx.y * M * N;
    const int bid = blockIdx.x;                    // 0..63
    const int bx = bid >> 4, by = bid & 15;        // 4 N-tiles x 16 M-tiles
    gemm256_body(A, Bt, plane, M, N, K, blockIdx.y * Ksub, Ksub, bx, by);
}

// delta main (cols 0..2047) split-K=2 into bf16 planes [2][4096][2048]:
// grid (128,2) = 256 blocks (1/CU). Bdot cols handled in delta_reduce's tail blocks.
__global__ __launch_bounds__(512, 2)
void gemm_delta256(const u16* __restrict__ A, const u16* __restrict__ Bt,
                   u16* __restrict__ planes, int M, int N, int K, int Ksub) {
    u16* plane = planes + (size_t)blockIdx.y * M * N;   // N = 2048
    const int bid = blockIdx.x;                    // 0..127
    const int xcd = bid & 7, lid = bid >> 3;       // lid 0..15
    const int by = xcd * 2 + (lid & 1), bx = lid >> 1;   // by 0..15, bx 0..7
    gemm256_body(A, Bt, plane, M, N, K, blockIdx.y * Ksub, Ksub, bx, by);
}

// ---------- 128x128 tile GEMM, BK=64, 4 waves x (4x4 frags), 32 KB LDS ----------
// EPI 0: bf16 store;  EPI 4: atomicAdd f32 (fallback fin)
template <int EPI>
__device__ __forceinline__
void gemm128_body(const u16* __restrict__ A, const u16* __restrict__ Bt,
                  void* __restrict__ out, int M, int N, int K, int Ksub) {
    __shared__ u16 As[128 * 64];
    __shared__ u16 Bs[128 * 64];
    int bx, by;
    swz(blockIdx.x, bx, by);
    const int tid = threadIdx.x;
    const int wave = tid >> 6, lane = tid & 63;
    const int row0 = by * 128, col0 = bx * 128;
    const int koff = blockIdx.y * Ksub;
    const int l16 = lane & 15, q = lane >> 4;
    const int sRow = lane >> 2, sK = (lane & 3) * 8;

    floatx4 acc[4][4];
#pragma unroll
    for (int i = 0; i < 4; ++i)
#pragma unroll
        for (int j = 0; j < 4; ++j) acc[i][j] = (floatx4){0.f, 0.f, 0.f, 0.f};

    const u16* gA = A + (size_t)(row0 + wave * 32 + sRow) * K + koff + sK;
    const u16* gB = Bt + (size_t)(col0 + wave * 32 + sRow) * K + koff + sK;
    u16* lA = As + wave * 1024;
    u16* lB = Bs + wave * 1024;
    const int rowb = (wave >> 1) * 64, colb = (wave & 1) * 64;

    for (int k0 = 0; k0 < Ksub; k0 += 64) {
#pragma unroll
        for (int h = 0; h < 2; ++h) {
            gl_lds16(gA + h * 32, lA + h * 4096);
            gl_lds16(gA + (size_t)16 * K + h * 32, lA + h * 4096 + 512);
            gl_lds16(gB + h * 32, lB + h * 4096);
            gl_lds16(gB + (size_t)16 * K + h * 32, lB + h * 4096 + 512);
        }
        gA += 64; gB += 64;
        __syncthreads();
#pragma unroll
        for (int h = 0; h < 2; ++h) {
            bf16x8 af[4], bfr[4];
#pragma unroll
            for (int mi = 0; mi < 4; ++mi)
                af[mi] = *(const bf16x8*)(As + h * 4096 + (rowb + mi * 16 + l16) * 32 + q * 8);
#pragma unroll
            for (int ni = 0; ni < 4; ++ni)
                bfr[ni] = *(const bf16x8*)(Bs + h * 4096 + (colb + ni * 16 + l16) * 32 + q * 8);
#pragma unroll
            for (int mi = 0; mi < 4; ++mi)
#pragma unroll
                for (int ni = 0; ni < 4; ++ni)
                    acc[mi][ni] = __builtin_amdgcn_mfma_f32_16x16x32_bf16(
                        af[mi], bfr[ni], acc[mi][ni], 0, 0, 0);
        }
        __syncthreads();
    }

    const int mB = row0 + rowb;
    const int nB = col0 + colb + l16;
    if constexpr (EPI == 0) {
        u16* o = (u16*)out;
#pragma unroll
        for (int mi = 0; mi < 4; ++mi)
#pragma unroll
            for (int ni = 0; ni < 4; ++ni)
#pragma unroll
                for (int rr = 0; rr < 4; ++rr)
                    o[(size_t)(mB + mi * 16 + q * 4 + rr) * N + nB + ni * 16] =
                        f2u(acc[mi][ni][rr]);
    } else {
        float* C = (float*)out;
#pragma unroll
        for (int mi = 0; mi < 4; ++mi)
#pragma unroll
            for (int ni = 0; ni < 4; ++ni)
#pragma unroll
                for (int rr = 0; rr < 4; ++rr)
                    atomicAdd(&C[(size_t)(mB + mi * 16 + q * 4 + rr) * N + nB + ni * 16],
                              acc[mi][ni][rr]);
    }
}

__global__ __launch_bounds__(256)
void gemm_fin(const u16* __restrict__ A, const u16* __restrict__ Bt,
              void* __restrict__ out, int M, int N, int K, int Ksub) {
    gemm128_body<4>(A, Bt, out, M, N, K, Ksub);
}

// out(=residual x) += sum of 4 bf16 planes; 8 elems/thread
__global__ __launch_bounds__(256)
void fin_reduce(const u16* __restrict__ planes, float* __restrict__ out) {
    const size_t PL = (size_t)4096 * 1024;
    const size_t idx = ((size_t)blockIdx.x * 256 + threadIdx.x) * 8;
    float acc[8] = {0.f, 0.f, 0.f, 0.f, 0.f, 0.f, 0.f, 0.f};
#pragma unroll
    for (int p = 0; p < 4; ++p) {
        ushort4 v0 = *(const ushort4*)(planes + p * PL + idx);
        ushort4 v1 = *(const ushort4*)(planes + p * PL + idx + 4);
        acc[0] += u2f(v0.x); acc[1] += u2f(v0.y); acc[2] += u2f(v0.z); acc[3] += u2f(v0.w);
        acc[4] += u2f(v1.x); acc[5] += u2f(v1.y); acc[6] += u2f(v1.z); acc[7] += u2f(v1.w);
    }
    float4 o0 = *(const float4*)(out + idx);
    float4 o1 = *(const float4*)(out + idx + 4);
    o0.x += acc[0]; o0.y += acc[1]; o0.z += acc[2]; o0.w += acc[3];
    o1.x += acc[4]; o1.y += acc[5]; o1.z += acc[6]; o1.w += acc[7];
    *(float4*)(out + idx) = o0;
    *(float4*)(out + idx + 4) = o1;
}

// ---------- delta reduce + fused bdot ----------
// blocks [0,4096): row r -> softplus(p0+p1+bd) rowsum (planes stride 2048)
// blocks [4096,4608): bdot split-K=8 -> Bdotn atomics (Bdotn pre-zeroed by conv)
__global__ __launch_bounds__(256)
void delta_reduce(const u16* __restrict__ planes, const float* __restrict__ bias,
                  float* __restrict__ dacc,
                  const u16* __restrict__ xsc, const u16* __restrict__ B16,
                  float* __restrict__ Bdotn) {
    const int t = threadIdx.x;
    if (blockIdx.x >= 4096) {
        // ---- bdot tail: 512 blocks x 4 waves; wave owns 16 rows x 16 n x 256 K ----
        const int bb = blockIdx.x - 4096;          // 0..511
        const int w = t >> 6, lane = t & 63;
        const int r0 = (bb & 63) * 64 + w * 16;
        const int k0 = (bb >> 6) * 256;
        const int l16 = lane & 15, q = lane >> 4;
        floatx4 acc = (floatx4){0.f, 0.f, 0.f, 0.f};
        const u16* pA = xsc + (size_t)(r0 + l16) * 2048 + k0 + q * 8;
        const u16* pB = B16 + (size_t)l16 * 2048 + k0 + q * 8;
#pragma unroll
        for (int kt = 0; kt < 256; kt += 32) {
            bf16x8 a = *(const bf16x8*)(pA + kt);
            bf16x8 b = *(const bf16x8*)(pB + kt);
            acc = __builtin_amdgcn_mfma_f32_16x16x32_bf16(a, b, acc, 0, 0, 0);
        }
#pragma unroll
        for (int rr = 0; rr < 4; ++rr)
            atomicAdd(&Bdotn[(size_t)l16 * 4096 + r0 + q * 4 + rr], acc[rr]);
        return;
    }
    const int r = blockIdx.x;            // 0..4095
    const size_t PL = (size_t)4096 * 2048;
    const u16* p0 = planes + (size_t)r * 2048 + t * 8;
    const u16* p1 = p0 + PL;
    ushort4 a0 = *(const ushort4*)p0;
    ushort4 a1 = *(const ushort4*)(p0 + 4);
    ushort4 b0 = *(const ushort4*)p1;
    ushort4 b1 = *(const ushort4*)(p1 + 4);
    float4 c0 = *(const float4*)(bias + t * 8);
    float4 c1 = *(const float4*)(bias + t * 8 + 4);
    float e[8];
    e[0] = u2f(a0.x) + u2f(b0.x) + c0.x;
    e[1] = u2f(a0.y) + u2f(b0.y) + c0.y;
    e[2] = u2f(a0.z) + u2f(b0.z) + c0.z;
    e[3] = u2f(a0.w) + u2f(b0.w) + c0.w;
    e[4] = u2f(a1.x) + u2f(b1.x) + c1.x;
    e[5] = u2f(a1.y) + u2f(b1.y) + c1.y;
    e[6] = u2f(a1.z) + u2f(b1.z) + c1.z;
    e[7] = u2f(a1.w) + u2f(b1.w) + c1.w;
    float sv = 0.f;
#pragma unroll
    for (int i = 0; i < 8; ++i)
        sv += (e[i] > 20.f) ? e[i] : log1pf(expf(e[i]));
#pragma unroll
    for (int off = 32; off > 0; off >>= 1)
        sv += __shfl_down(sv, off, 64);
    __shared__ float wsum[4];
    const int wave = t >> 6, lane = t & 63;
    if (lane == 0) wsum[wave] = sv;
    __syncthreads();
    if (t == 0) dacc[r] = wsum[0] + wsum[1] + wsum[2] + wsum[3];
}

// ---------- delta GEMM fallback (ws too small): 128M x 64N tile, BK=128 ----------
__global__ __launch_bounds__(256)
void gemm_delta(const u16* __restrict__ A, const u16* __restrict__ Bt,
                float* __restrict__ dacc, const float* __restrict__ bias,
                float* __restrict__ Bdotn, int M, int N, int K) {
    __shared__ u16 As[128 * 128];
    __shared__ u16 Bs[64 * 128];
    int bx, by;
    swz(blockIdx.x, bx, by);
    const int tid = threadIdx.x;
    const int wave = tid >> 6, lane = tid & 63;
    const int row0 = by * 128, col0 = bx * 64;
    const int l16 = lane & 15, q = lane >> 4;
    const int sRow = lane >> 2, sK = (lane & 3) * 8;

    floatx4 acc[2][4];
#pragma unroll
    for (int i = 0; i < 2; ++i)
#pragma unroll
        for (int j = 0; j < 4; ++j) acc[i][j] = (floatx4){0.f, 0.f, 0.f, 0.f};

    const u16* gA = A + (size_t)(row0 + wave * 32 + sRow) * K + sK;
    const u16* gB = Bt + (size_t)(col0 + wave * 16 + sRow) * K + sK;
    u16* lA = As + wave * 1024;
    u16* lB = Bs + wave * 512;
    const int rowb = wave * 32;

    for (int k0 = 0; k0 < K; k0 += 128) {
#pragma unroll
        for (int h = 0; h < 4; ++h) {
            gl_lds16(gA + h * 32, lA + h * 4096);
            gl_lds16(gA + (size_t)16 * K + h * 32, lA + h * 4096 + 512);
            gl_lds16(gB + h * 32, lB + h * 2048);
        }
        gA += 128; gB += 128;
        __syncthreads();
#pragma unroll
        for (int h = 0; h < 4; ++h) {
            bf16x8 af[2], bfr[4];
#pragma unroll
            for (int mi = 0; mi < 2; ++mi)
                af[mi] = *(const bf16x8*)(As + h * 4096 + (rowb + mi * 16 + l16) * 32 + q * 8);
#pragma unroll
            for (int ni = 0; ni < 4; ++ni)
                bfr[ni] = *(const bf16x8*)(Bs + h * 2048 + (ni * 16 + l16) * 32 + q * 8);
#pragma unroll
            for (int mi = 0; mi < 2; ++mi)
#pragma unroll
                for (int ni = 0; ni < 4; ++ni)
                    acc[mi][ni] = __builtin_amdgcn_mfma_f32_16x16x32_bf16(
                        af[mi], bfr[ni], acc[mi][ni], 0, 0, 0);
        }
        __syncthreads();
    }

    const int mB = row0 + rowb;
    const int nB = col0 + l16;
    if (col0 < 2048) {
#pragma unroll
        for (int mi = 0; mi < 2; ++mi) {
#pragma unroll
            for (int rr = 0; rr < 4; ++rr) {
                float sv = 0.f;
#pragma unroll
                for (int ni = 0; ni < 4; ++ni) {
                    float t2 = acc[mi][ni][rr] + bias[nB + ni * 16];
                    sv += (t2 > 20.f) ? t2 : log1pf(expf(t2));
                }
#pragma unroll
                for (int off = 1; off < 16; off <<= 1)
                    sv += __shfl_xor(sv, off, 64);
                if (l16 == 0)
                    atomicAdd(&dacc[mB + mi * 16 + q * 4 + rr], sv);
            }
        }
    } else {
#pragma unroll
        for (int mi = 0; mi < 2; ++mi)
#pragma unroll
            for (int rr = 0; rr < 4; ++rr)
                Bdotn[(size_t)l16 * 4096 + mB + mi * 16 + q * 4 + rr] =
                    acc[mi][0][rr];
    }
}

// ---------- lean conv(K=4)+SiLU, 4 rows/block (1024 blocks) + delta_acc/Bdotn zero ----------
__global__ __launch_bounds__(256) void conv_silu_kernel(const u16* __restrict__ xg,
                                                        const float* __restrict__ conv_w,
                                                        const float* __restrict__ conv_b,
                                                        u16* __restrict__ xsc,
                                                        float* __restrict__ delta_acc,
                                                        float* __restrict__ Bdotn) {
    int r0 = blockIdx.x * 4;                  // 4 rows/block; 2048 % 4 == 0
    int l0 = r0 & 2047, bb = r0 >> 11;
    int t = threadIdx.x, d8 = t * 8;
    if (t < 4) delta_acc[r0 + t] = 0.f;       // zero before fallback path's atomics
    if (t < 64) Bdotn[(size_t)blockIdx.x * 64 + t] = 0.f;   // 1024*64 = 16*4096 exact

    ushort4 rw[7][2];                         // rows l0-3 .. l0+3
#pragma unroll
    for (int j = 0; j < 7; ++j) {
        int ls = l0 + j - 3;
        if (ls >= 0) {
            const u16* row = xg + (size_t)((bb << 11) + ls) * 4096 + d8;
            rw[j][0] = *(const ushort4*)row;
            rw[j][1] = *(const ushort4*)(row + 4);
        } else {
            rw[j][0] = (ushort4){0, 0, 0, 0};
            rw[j][1] = (ushort4){0, 0, 0, 0};
        }
    }
    float w[8][4];
#pragma unroll
    for (int j = 0; j < 8; ++j) {
        float4 wv = *(const float4*)(conv_w + (size_t)(d8 + j) * 4);
        w[j][0] = wv.x; w[j][1] = wv.y; w[j][2] = wv.z; w[j][3] = wv.w;
    }
    float cb[8];
    {
        float4 b0 = *(const float4*)(conv_b + d8);
        float4 b1 = *(const float4*)(conv_b + d8 + 4);
        cb[0] = b0.x; cb[1] = b0.y; cb[2] = b0.z; cb[3] = b0.w;
        cb[4] = b1.x; cb[5] = b1.y; cb[6] = b1.z; cb[7] = b1.w;
    }
#pragma unroll
    for (int i = 0; i < 4; ++i) {
        float xs[8];
#pragma unroll
        for (int j = 0; j < 8; ++j) xs[j] = cb[j];
#pragma unroll
        for (int k = 0; k < 4; ++k) {
            ushort4 u0 = rw[i + k][0], u1 = rw[i + k][1];
            xs[0] += w[0][k] * u2f(u0.x); xs[1] += w[1][k] * u2f(u0.y);
            xs[2] += w[2][k] * u2f(u0.z); xs[3] += w[3][k] * u2f(u0.w);
            xs[4] += w[4][k] * u2f(u1.x); xs[5] += w[5][k] * u2f(u1.y);
            xs[6] += w[6][k] * u2f(u1.z); xs[7] += w[7][k] * u2f(u1.w);
        }
        ushort4 o0, o1;
        o0.x = f2u(xs[0] / (1.f + expf(-xs[0])));
        o0.y = f2u(xs[1] / (1.f + expf(-xs[1])));
        o0.z = f2u(xs[2] / (1.f + expf(-xs[2])));
        o0.w = f2u(xs[3] / (1.f + expf(-xs[3])));
        o1.x = f2u(xs[4] / (1.f + expf(-xs[4])));
        o1.y = f2u(xs[5] / (1.f + expf(-xs[5])));
        o1.z = f2u(xs[6] / (1.f + expf(-xs[6])));
        o1.w = f2u(xs[7] / (1.f + expf(-xs[7])));
        u16* orow = xsc + (size_t)(r0 + i) * 2048 + d8;
        *(ushort4*)orow = o0;
        *(ushort4*)(orow + 4) = o1;
    }
}

// ---------- selective scan: 32 chains, 256 threads (4 waves) each ----------
__global__ __launch_bounds__(256) void scan_kernel(const float* __restrict__ delta_acc,
                                                   const float* __restrict__ Bdotn,
                                                   const float* __restrict__ A_log,
                                                   float* __restrict__ hsn) {
    int chain = blockIdx.x;                 // 0..31
    int b = chain >> 4, n = chain & 15;
    int t = threadIdx.x;                    // 0..255
    int wave = t >> 6, lane = t & 63;
    __shared__ float sd[2048], sb[2048];
    __shared__ float wA[4], wB[4];
#pragma unroll
    for (int m = 0; m < 2; ++m) {
        int idx = (m * 256 + t) * 4;
        *(float4*)(sd + idx) = *(const float4*)(delta_acc + b * 2048 + idx);
        *(float4*)(sb + idx) = *(const float4*)(Bdotn + (size_t)n * 4096 + b * 2048 + idx);
    }
    __syncthreads();
    float An = -expf(A_log[n]);
    int base = t * 8;
    float a[8], bb[8];
#pragma unroll
    for (int i = 0; i < 8; ++i) {
        float dl = sd[base + i] * (1.f / 2048.f);
        a[i] = expf(dl * An);
        bb[i] = sb[base + i] * dl;
    }
    float Aacc = 1.f, Bacc = 0.f;
#pragma unroll
    for (int i = 0; i < 8; ++i) {
        Bacc = a[i] * Bacc + bb[i];
        Aacc = a[i] * Aacc;
    }
#pragma unroll
    for (int d = 1; d < 64; d <<= 1) {
        float Ap = __shfl_up(Aacc, d, 64);
        float Bp = __shfl_up(Bacc, d, 64);
        if (lane >= d) {
            Bacc = Aacc * Bp + Bacc;
            Aacc = Aacc * Ap;
        }
    }
    if (lane == 63) { wA[wave] = Aacc; wB[wave] = Bacc; }
    float eA = __shfl_up(Aacc, 1, 64);
    float eB = __shfl_up(Bacc, 1, 64);
    if (lane == 0) { eA = 1.f; eB = 0.f; }
    __syncthreads();
    float pB = 0.f;
#pragma unroll
    for (int w = 0; w < 3; ++w)
        if (w < wave) pB = wA[w] * pB + wB[w];
    float h = eA * pB + eB;
#pragma unroll
    for (int i = 0; i < 8; ++i) {
        h = a[i] * h + bb[i];
        sd[base + i] = h;
    }
    __syncthreads();
#pragma unroll
    for (int m = 0; m < 2; ++m) {
        int idx = (m * 256 + t) * 4;
        *(float4*)(hsn + (size_t)n * 4096 + b * 2048 + idx) = *(const float4*)(sd + idx);
    }
}

// ---------- ymid = (hs·C_mat[d,:] + D_vec*xsc) * silu(gate), bf16 out ----------
// grid (4, 256): block owns d-range [bx*512, +512), rows [by*16, +16). 1024 blocks.
__global__ __launch_bounds__(256) void ymid_kernel(const float* __restrict__ hsn,
                                                   const float* __restrict__ C_mat,
                                                   const float* __restrict__ D_vec,
                                                   const u16* __restrict__ xsc,
                                                   const u16* __restrict__ xg,
                                                   u16* __restrict__ ymid) {
    const int t = threadIdx.x;
    const int d0 = blockIdx.x * 512 + t * 2;
    const int r0 = blockIdx.y * 16;
    __shared__ float hsv[16 * 16];
    {
        int rl = t >> 4, nn = t & 15;          // t covers all 256 entries
        hsv[t] = hsn[(size_t)nn * 4096 + r0 + rl];
    }
    float c0[16], c1[16];
#pragma unroll
    for (int k = 0; k < 4; ++k) {
        float4 v0 = *(const float4*)(C_mat + (size_t)d0 * 16 + k * 4);
        float4 v1 = *(const float4*)(C_mat + (size_t)(d0 + 1) * 16 + k * 4);
        c0[k * 4 + 0] = v0.x; c0[k * 4 + 1] = v0.y; c0[k * 4 + 2] = v0.z; c0[k * 4 + 3] = v0.w;
        c1[k * 4 + 0] = v1.x; c1[k * 4 + 1] = v1.y; c1[k * 4 + 2] = v1.z; c1[k * 4 + 3] = v1.w;
    }
    const float dv0 = D_vec[d0], dv1 = D_vec[d0 + 1];
    __syncthreads();
#pragma unroll 4
    for (int rl = 0; rl < 16; ++rl) {
        const int r = r0 + rl;
        float h0 = 0.f, h1 = 0.f;
#pragma unroll
        for (int nn = 0; nn < 16; ++nn) {
            float hv = hsv[rl * 16 + nn];      // same addr across lanes: broadcast
            h0 += hv * c0[nn];
            h1 += hv * c1[nn];
        }
        unsigned int xv = *(const unsigned int*)(xsc + (size_t)r * 2048 + d0);
        unsigned int gv = *(const unsigned int*)(xg + (size_t)r * 4096 + 2048 + d0);
        float x0 = u2f((u16)(xv & 0xffffu)), x1 = u2f((u16)(xv >> 16));
        float g0 = u2f((u16)(gv & 0xffffu)), g1 = u2f((u16)(gv >> 16));
        float y0 = (h0 + dv0 * x0) * (g0 / (1.f + expf(-g0)));
        float y1 = (h1 + dv1 * x1) * (g1 / (1.f + expf(-g1)));
        unsigned int o = (unsigned int)f2u(y0) | ((unsigned int)f2u(y1) << 16);
        *(unsigned int*)(ymid + (size_t)r * 2048 + d0) = o;
    }
}

extern "C" void kernel_launch(void* const* d_in, const int* in_sizes, int n_in,
                              void* d_out, int out_size, void* d_ws, size_t ws_size,
                              hipStream_t stream) {
    (void)in_sizes; (void)n_in;
    const float* x      = (const float*)d_in[0];
    const float* ln_g   = (const float*)d_in[1];
    const float* ln_b   = (const float*)d_in[2];
    const float* W_in   = (const float*)d_in[3];
    const float* conv_w = (const float*)d_in[4];
    const float* conv_b = (const float*)d_in[5];
    const float* A_log  = (const float*)d_in[6];
    const float* B_mat  = (const float*)d_in[7];
    const float* C_mat  = (const float*)d_in[8];
    const float* D_vec  = (const float*)d_in[9];
    const float* Wd     = (const float*)d_in[10];
    const float* bd     = (const float*)d_in[11];
    const float* W_out  = (const float*)d_in[12];
    float* out = (float*)d_out;

    // ---- workspace layout (time-overlaid) ----
    char* base = (char*)d_ws;
    u16* Wt_in  = (u16*)base;                          // 4096x1024 bf16 (bufA lo)
    u16* h_ln   = (u16*)base + 4096ull * 1024;         // 4096x1024 bf16 (bufA hi)
    u16* ymid   = (u16*)base;                          // 4096x2048 bf16 (reuse bufA post-GEMM1)
    u16* Wt_ext = (u16*)(base + (16ull << 20));        // 2112x2048 bf16 (Wd^T + B_mat + pad)
    u16* Wt_out = (u16*)(base + (25ull << 20));        // 1024x2048 bf16 (4 MiB)
    u16* xg     = (u16*)(base + (29ull << 20));        // 4096x4096 bf16 (32 MiB)
    u16* xsc    = (u16*)(base + (61ull << 20));        // 4096x2048 bf16 (16 MiB)
    float* delta_acc = (float*)(base + (77ull << 20)); // 4096 f32
    float* Bdotn = delta_acc + 4096;                   // [16][4096] f32
    float* hsn   = Bdotn + 16 * 4096;                  // [16][4096] f32
    u16* planes  = (u16*)(base + (78ull << 20));       // delta: 2 x [4096][2048] bf16 = 32 MiB
    u16* fplanes = (u16*)(base + (78ull << 20));       // fin:   4 x [4096][1024] bf16 = 32 MiB (delta planes dead)
    size_t needed = (77ull << 20) + 4096ull * 4 * (1 + 2 * 16);
    size_t needed_sk = (78ull << 20) + 2ull * 4096 * 2176 * 2;   // 112 MiB (covers 32 MiB planes)

    if (needed > ws_size) {
        hipMemsetAsync(d_out, 0x7F, (size_t)out_size * 4, stream);  // finite sentinel
        return;
    }
    const bool use_sk = (ws_size >= needed_sk);

    // 1. prep: transposes (vectorized stores) + B_mat pad + layernorm + out=x
    prep_kernel<<<14848, 256, 0, stream>>>(W_in, Wt_in, Wd, Wt_ext, W_out, Wt_out,
                                           B_mat, x, ln_g, ln_b, h_ln, out);
    // 2. xg = h @ W_in : 256x256 8-phase kernel (T2-swizzled), 256 blocks, 512 threads
    gemm_xg256<<<256, 512, 0, stream>>>(h_ln, Wt_in, xg, 4096, 4096, 1024);
    // 3. conv + silu (+delta_acc/Bdotn zero), 4 rows/block, 1024 blocks
    conv_silu_kernel<<<1024, 256, 0, stream>>>(xg, conv_w, conv_b, xsc, delta_acc, Bdotn);
    // 4. delta GEMM
    if (use_sk) {
        // main 2048 cols: 256x256 8-phase split-K=2 -> bf16 planes; (128,2) = 256 blocks
        gemm_delta256<<<dim3(128, 2), 512, 0, stream>>>(xsc, Wt_ext, planes,
                                                        4096, 2048, 2048, 1024);
        // combine + bias + softplus rowsum -> delta_acc; tail blocks do bdot -> Bdotn
        delta_reduce<<<4608, 256, 0, stream>>>(planes, bd, delta_acc,
                                               xsc, Wt_ext + (size_t)2048 * 2048, Bdotn);
    } else {
        gemm_delta<<<1056, 256, 0, stream>>>(xsc, Wt_ext, delta_acc, bd, Bdotn,
                                             4096, 2112, 2048);
    }
    // 5. selective scan: 32 chains x 256 threads
    scan_kernel<<<32, 256, 0, stream>>>(delta_acc, Bdotn, A_log, hsn);
    // 6. ymid (into bufA; h_ln/Wt_in dead): C-in-registers, 16 rows/block, 1024 blocks
    ymid_kernel<<<dim3(4, 256), 256, 0, stream>>>(hsn, C_mat, D_vec, xsc, xg, ymid);
    // 7. out += ymid @ W_out
    if (use_sk) {
        // 256x256 8-phase split-K=4 into bf16 planes: (64,4) = 256 blocks (1/CU)
        gemm_fin256<<<dim3(64, 4), 512, 0, stream>>>(ymid, Wt_out, fplanes,
                                                     4096, 1024, 2048, 512);
        fin_reduce<<<2048, 256, 0, stream>>>(fplanes, out);
    } else {
        gemm_fin<<<dim3(256, 2), 256, 0, stream>>>(ymid, Wt_out, out, 4096, 1024, 2048, 1024);
    }
}